// Round 2
// baseline (2112.103 us; speedup 1.0000x reference)
//
#include <hip/hip_runtime.h>
#include <cmath>

// ============================================================================
// DPRNN block (intra BiGRU + inter Skip-GRU), all fp32.
// NUMERICS: inter skip-GRU binary gate round(sigmoid(h@Wp)) -> keep fp32.
// Round 2: inter GRU restructured:
//   - t-chunked (nt steps/launch) instead of seq-chunked -> all 1024 seqs,
//     512 blocks (2 seqs each) = 2 blocks/CU; h/ut/u state in ws.
//   - U_zr in registers (64/thread), U_hh in LDS (transposed + XOR-swizzled).
//   - in-wave shfl_xor k-split reduce -> 2 barriers/step (was 4).
// ============================================================================

__device__ __forceinline__ float sigf(float x) { return 1.0f / (1.0f + expf(-x)); }

// ---------------------------------------------------------------- fill ones
__global__ __launch_bounds__(256) void k_fill_ones(float* __restrict__ p, int n) {
  int i = blockIdx.x * 256 + threadIdx.x;
  if (i < n) p[i] = 1.0f;
}

// ---------------------------------------------------------------- GEMM (xw precompute)
enum { MA_X_FWD = 0, MA_X_BWD = 1, MA_INTER = 2 };

template <int MODE>
__global__ __launch_bounds__(256) void k_gemm_xw(
    const float* __restrict__ A0, const float* __restrict__ A1,
    const float* __restrict__ Bm, const float* __restrict__ bias,
    float* __restrict__ Cm, long M0, int N, int K, int KT)
{
  __shared__ float As[16][68];
  __shared__ float Bs[16][68];
  const int tid = threadIdx.x;
  const int tx = tid & 15, ty = tid >> 4;
  const long row0g = M0 + (long)blockIdx.x * 64;
  const int col0 = blockIdx.y * 64;
  const int lr = tid >> 2;
  const int lk4 = (tid & 3) * 4;
  const int bk = tid >> 4;
  const int bc4 = (tid & 15) * 4;
  float acc[4][4];
#pragma unroll
  for (int i = 0; i < 4; ++i)
#pragma unroll
    for (int j = 0; j < 4; ++j) acc[i][j] = 0.f;

  for (int kt = 0; kt < KT; ++kt) {
    const int k0 = kt * 16;
    {
      const long rg = row0g + lr;
      float v0, v1, v2, v3;
      if (MODE == MA_X_FWD) {
        const float4 a4 = *reinterpret_cast<const float4*>(&A0[rg * 128 + k0 + lk4]);
        v0 = a4.x; v1 = a4.y; v2 = a4.z; v3 = a4.w;
      } else if (MODE == MA_X_BWD) {
        const long s = rg >> 6; const int t = (int)(rg & 63);
        const float4 a4 =
            *reinterpret_cast<const float4*>(&A0[(s * 64 + (63 - t)) * 128 + k0 + lk4]);
        v0 = a4.x; v1 = a4.y; v2 = a4.z; v3 = a4.w;
      } else {  // MA_INTER: rg = l*1024 + n (l global time index)
        const int n = (int)(rg & 1023);
        const int l = (int)(rg >> 10);
        const long rowc = ((long)(n >> 6) * 200 + l) * 64 + (n & 63);
        const long base = rowc * 128;
        float vv[4];
#pragma unroll
        for (int i = 0; i < 4; ++i) {
          const int k = k0 + lk4 + i;
          vv[i] = (k < 128) ? A0[base + k] : ((k == 128) ? A1[rowc] : 0.f);
        }
        v0 = vv[0]; v1 = vv[1]; v2 = vv[2]; v3 = vv[3];
      }
      As[lk4 + 0][lr] = v0;
      As[lk4 + 1][lr] = v1;
      As[lk4 + 2][lr] = v2;
      As[lk4 + 3][lr] = v3;
    }
    {
      const int k = k0 + bk;
      float4 b4 = make_float4(0.f, 0.f, 0.f, 0.f);
      if (k < K) b4 = *reinterpret_cast<const float4*>(&Bm[(long)k * N + col0 + bc4]);
      *reinterpret_cast<float4*>(&Bs[bk][bc4]) = b4;
    }
    __syncthreads();
#pragma unroll
    for (int kk = 0; kk < 16; ++kk) {
      const float4 a4 = *reinterpret_cast<const float4*>(&As[kk][ty * 4]);
      const float4 b4 = *reinterpret_cast<const float4*>(&Bs[kk][tx * 4]);
      const float av[4] = {a4.x, a4.y, a4.z, a4.w};
      const float bv[4] = {b4.x, b4.y, b4.z, b4.w};
#pragma unroll
      for (int i = 0; i < 4; ++i)
#pragma unroll
        for (int j = 0; j < 4; ++j) acc[i][j] = fmaf(av[i], bv[j], acc[i][j]);
    }
    __syncthreads();
  }
  const float4 bi4 = *reinterpret_cast<const float4*>(&bias[col0 + tx * 4]);
  const float bv[4] = {bi4.x, bi4.y, bi4.z, bi4.w};
#pragma unroll
  for (int i = 0; i < 4; ++i) {
    const long rl = (long)blockIdx.x * 64 + ty * 4 + i;
    float4 o;
    o.x = acc[i][0] + bv[0];
    o.y = acc[i][1] + bv[1];
    o.z = acc[i][2] + bv[2];
    o.w = acc[i][3] + bv[3];
    *reinterpret_cast<float4*>(&Cm[rl * (long)N + col0 + tx * 4]) = o;
  }
}

// ---------------------------------------------------------------- intra GRU (unchanged)
__global__ __launch_bounds__(256, 2) void k_gru_intra(
    const float* __restrict__ xwf, const float* __restrict__ xwb,
    const float* __restrict__ Uf, const float* __restrict__ Ub,
    float* __restrict__ rnn, int nseq)
{
  const int dir = blockIdx.y;
  const float* __restrict__ xw = dir ? xwb : xwf;
  const float* __restrict__ U = dir ? Ub : Uf;
  __shared__ float Us[64 * 192];
  __shared__ float hs[8][64];
  __shared__ float zs[8][64];
  __shared__ float rhs[8][64];
  const int tid = threadIdx.x;
#pragma unroll
  for (int i = 0; i < 12; ++i) {
    *reinterpret_cast<float4*>(&Us[(tid + i * 256) * 4]) =
        *reinterpret_cast<const float4*>(&U[(tid + i * 256) * 4]);
  }
  reinterpret_cast<float*>(hs)[tid] = 0.f;
  reinterpret_cast<float*>(hs)[tid + 256] = 0.f;
  __syncthreads();
  const int sA = tid >> 5;
  const int cA = tid & 31;
  const long s0 = (long)blockIdx.x * 8;
  const long xbase = (s0 + sA) * 64;
  float4 xzr = *reinterpret_cast<const float4*>(&xw[(xbase + 0) * 192 + 4 * cA]);
  float2 xh = *reinterpret_cast<const float2*>(&xw[(xbase + 0) * 192 + 128 + 2 * cA]);
  for (int t = 0; t < 64; ++t) {
    float4 xzr_n = make_float4(0.f, 0.f, 0.f, 0.f);
    float2 xh_n = make_float2(0.f, 0.f);
    if (t < 63) {
      xzr_n = *reinterpret_cast<const float4*>(&xw[(xbase + t + 1) * 192 + 4 * cA]);
      xh_n = *reinterpret_cast<const float2*>(&xw[(xbase + t + 1) * 192 + 128 + 2 * cA]);
    }
    float a0 = 0.f, a1 = 0.f, a2 = 0.f, a3 = 0.f;
#pragma unroll
    for (int k4 = 0; k4 < 16; ++k4) {
      const float4 h4 = *reinterpret_cast<const float4*>(&hs[sA][4 * k4]);
      const float hv[4] = {h4.x, h4.y, h4.z, h4.w};
#pragma unroll
      for (int i = 0; i < 4; ++i) {
        const float4 u4 =
            *reinterpret_cast<const float4*>(&Us[(4 * k4 + i) * 192 + 4 * cA]);
        a0 = fmaf(hv[i], u4.x, a0);
        a1 = fmaf(hv[i], u4.y, a1);
        a2 = fmaf(hv[i], u4.z, a2);
        a3 = fmaf(hv[i], u4.w, a3);
      }
    }
    if (cA < 16) {
      float4 zq;
      zq.x = sigf(xzr.x + a0);
      zq.y = sigf(xzr.y + a1);
      zq.z = sigf(xzr.z + a2);
      zq.w = sigf(xzr.w + a3);
      *reinterpret_cast<float4*>(&zs[sA][4 * cA]) = zq;
    } else {
      const int j0 = 4 * cA - 64;
      const float4 h4 = *reinterpret_cast<const float4*>(&hs[sA][j0]);
      float4 rq;
      rq.x = sigf(xzr.x + a0) * h4.x;
      rq.y = sigf(xzr.y + a1) * h4.y;
      rq.z = sigf(xzr.z + a2) * h4.z;
      rq.w = sigf(xzr.w + a3) * h4.w;
      *reinterpret_cast<float4*>(&rhs[sA][j0]) = rq;
    }
    __syncthreads();
    float b0 = 0.f, b1 = 0.f;
#pragma unroll
    for (int k4 = 0; k4 < 16; ++k4) {
      const float4 r4 = *reinterpret_cast<const float4*>(&rhs[sA][4 * k4]);
      const float rv[4] = {r4.x, r4.y, r4.z, r4.w};
#pragma unroll
      for (int i = 0; i < 4; ++i) {
        const float2 u2 =
            *reinterpret_cast<const float2*>(&Us[(4 * k4 + i) * 192 + 128 + 2 * cA]);
        b0 = fmaf(rv[i], u2.x, b0);
        b1 = fmaf(rv[i], u2.y, b1);
      }
    }
    {
      const int j0 = 2 * cA;
      const float hh0 = tanhf(xh.x + b0);
      const float hh1 = tanhf(xh.y + b1);
      const float z0 = zs[sA][j0], z1 = zs[sA][j0 + 1];
      const float ho0 = hs[sA][j0], ho1 = hs[sA][j0 + 1];
      const float hn0 = z0 * ho0 + (1.f - z0) * hh0;
      const float hn1 = z1 * ho1 + (1.f - z1) * hh1;
      hs[sA][j0] = hn0;
      hs[sA][j0 + 1] = hn1;
      const int tt = dir ? (63 - t) : t;
      float2 st; st.x = hn0; st.y = hn1;
      *reinterpret_cast<float2*>(
          &rnn[((s0 + sA) * 64 + tt) * 128 + dir * 64 + j0]) = st;
    }
    __syncthreads();
    xzr = xzr_n; xh = xh_n;
  }
}

// ---------------------------------------------------------------- inter skip-GRU v2
// 2 seqs/block, 512 blocks, 512 threads. t-chunked [t0, t0+nt).
// xw layout: [nt][1024][384]; rnn: [nt][1024][128].
// Phase A (zr cols 0..255): wave w -> cols 32w..32w+31; lane half = k-split(64).
// Phase B (hh cols 0..127): wave w -> seq (w>>2), cols 32(w&3)..+31; half = k-split.
// U_zr: 64 regs/thread. U_hh: LDS transposed, 16B XOR-swizzled.
__global__ __launch_bounds__(512, 4) void k_gru_inter2(
    const float* __restrict__ xw, const float* __restrict__ Ui,
    const float* __restrict__ Wp, const float* __restrict__ bp,
    float* __restrict__ rnn, float* __restrict__ gates,
    float* __restrict__ hstate, float* __restrict__ ustate,
    int t0, int nt)
{
  __shared__ float Uh[128 * 128];  // [col][k] swizzled at 16B granularity
  __shared__ float h_s[2][128];
  __shared__ float z_s[2][128];
  __shared__ float rh_s[2][128];
  __shared__ float wp_s[128];
  __shared__ float pred[2][4];
  __shared__ float ut_s[2];
  __shared__ float u_s[2];
  const int tid = threadIdx.x;
  const int w = tid >> 6, lane = tid & 63, half = lane >> 5, lcol = lane & 31;
  const int n0 = blockIdx.x * 2;
  const int colA = w * 32 + lcol;        // 0..255
  const int ksA = half;
  const int seqB = w >> 2;               // 0..1
  const int colB = (w & 3) * 32 + lcol;  // 0..127
  const int ksB = half;

  // U_zr -> registers (column colA, k-slice ksA*64..+63)
  float uzr[64];
#pragma unroll
  for (int k = 0; k < 64; ++k) uzr[k] = Ui[(long)(ksA * 64 + k) * 384 + colA];

  // U_hh -> LDS, transposed ([col][k]) with 16B-chunk XOR swizzle on k
  for (int idx = tid; idx < 16384; idx += 512) {
    const int k = idx >> 7, c = idx & 127;
    const float v = Ui[(long)k * 384 + 256 + c];
    Uh[c * 128 + (((k >> 2) ^ (c & 31)) << 2) + (k & 3)] = v;
  }
  if (tid < 256) {
    const int s = tid >> 7, c = tid & 127;
    h_s[s][c] = (t0 == 0) ? 0.f : hstate[(long)(n0 + s) * 128 + c];
  }
  if (tid < 128) wp_s[tid] = Wp[tid];
  if (tid < 2) {
    ut_s[tid] = (t0 == 0) ? 1.0f : ustate[n0 + tid];
    u_s[tid] = (t0 == 0) ? 1.0f : ustate[1024 + n0 + tid];
  }
  const float bp0 = bp[0];
  __syncthreads();

  // prefetch xw for dl=0 (lanes<32 only)
  float xa0 = 0.f, xa1 = 0.f, xb0 = 0.f;
  if (lane < 32) {
    xa0 = xw[(long)n0 * 384 + colA];
    xa1 = xw[(long)(n0 + 1) * 384 + colA];
    xb0 = xw[(long)(n0 + seqB) * 384 + 256 + colB];
  }

  for (int dl = 0; dl < nt; ++dl) {
    // issue next-step xw loads early (clamped at tail)
    const int dn = (dl + 1 < nt) ? dl + 1 : dl;
    float xa0n = 0.f, xa1n = 0.f, xbn = 0.f;
    if (lane < 32) {
      xa0n = xw[((long)dn * 1024 + n0) * 384 + colA];
      xa1n = xw[((long)dn * 1024 + n0 + 1) * 384 + colA];
      xbn = xw[((long)dn * 1024 + n0 + seqB) * 384 + 256 + colB];
    }
    // ---- phase A: z/r dots (both seqs), k-split combined via shfl ----
    float a0 = 0.f, a1 = 0.f;
    const int hb = ksA * 64;
#pragma unroll
    for (int k4 = 0; k4 < 16; ++k4) {
      const float4 h0 = *reinterpret_cast<const float4*>(&h_s[0][hb + 4 * k4]);
      const float4 h1 = *reinterpret_cast<const float4*>(&h_s[1][hb + 4 * k4]);
      a0 = fmaf(h0.x, uzr[4 * k4 + 0], a0);
      a0 = fmaf(h0.y, uzr[4 * k4 + 1], a0);
      a0 = fmaf(h0.z, uzr[4 * k4 + 2], a0);
      a0 = fmaf(h0.w, uzr[4 * k4 + 3], a0);
      a1 = fmaf(h1.x, uzr[4 * k4 + 0], a1);
      a1 = fmaf(h1.y, uzr[4 * k4 + 1], a1);
      a1 = fmaf(h1.z, uzr[4 * k4 + 2], a1);
      a1 = fmaf(h1.w, uzr[4 * k4 + 3], a1);
    }
    a0 += __shfl_xor(a0, 32);
    a1 += __shfl_xor(a1, 32);
    if (lane < 32) {
      const float p0 = xa0 + a0;
      const float p1 = xa1 + a1;
      if (colA < 128) {
        z_s[0][colA] = sigf(p0);
        z_s[1][colA] = sigf(p1);
      } else {
        const int c = colA - 128;
        rh_s[0][c] = sigf(p0) * h_s[0][c];
        rh_s[1][c] = sigf(p1) * h_s[1][c];
      }
    }
    __syncthreads();  // barrier 1: z_s, rh_s ready
    // ---- phase B: hh dots (own seq), U_hh from swizzled LDS ----
    float b = 0.f;
    const int rb = ksB * 64;
#pragma unroll
    for (int k4 = 0; k4 < 16; ++k4) {
      const float4 r4 = *reinterpret_cast<const float4*>(&rh_s[seqB][rb + 4 * k4]);
      const int chunk = ((ksB << 4) + k4) ^ (colB & 31);
      const float4 u4 = *reinterpret_cast<const float4*>(&Uh[colB * 128 + (chunk << 2)]);
      b = fmaf(r4.x, u4.x, b);
      b = fmaf(r4.y, u4.y, b);
      b = fmaf(r4.z, u4.z, b);
      b = fmaf(r4.w, u4.w, b);
    }
    b += __shfl_xor(b, 32);
    if (lane < 32) {
      const float pre = xb0 + b;
      const float hh = tanhf(pre);
      const float z = z_s[seqB][colB];
      const float ho = h_s[seqB][colB];
      const float hn = z * ho + (1.f - z) * hh;
      const float u = u_s[seqB];  // binary 0/1 -> exact blend
      const float hq = u * hn + (1.f - u) * ho;
      rnn[((long)dl * 1024 + n0 + seqB) * 128 + colB] = hq;
      h_s[seqB][colB] = hq;
      // delta partial: reduce 32 lanes
      float p = hq * wp_s[colB];
      p += __shfl_xor(p, 16);
      p += __shfl_xor(p, 8);
      p += __shfl_xor(p, 4);
      p += __shfl_xor(p, 2);
      p += __shfl_xor(p, 1);
      if (lcol == 0) pred[seqB][w & 3] = p;
    }
    __syncthreads();  // barrier 2: h_s, pred ready
    if (tid < 2) {
      const float pp = pred[tid][0] + pred[tid][1] + pred[tid][2] + pred[tid][3];
      const float delta = sigf(pp + bp0);
      const float u = u_s[tid], ut = ut_s[tid];
      gates[(long)(n0 + tid) * 200 + t0 + dl] = u;
      const float utn = u * delta + (1.f - u) * (ut + fminf(delta, 1.f - ut));
      ut_s[tid] = utn;
      u_s[tid] = rintf(utn);  // half-to-even, matches jnp.round
    }
    xa0 = xa0n; xa1 = xa1n; xb0 = xbn;
  }
  // save state for next t-chunk
  if (tid < 256) {
    const int s = tid >> 7, c = tid & 127;
    hstate[(long)(n0 + s) * 128 + c] = h_s[s][c];
  }
  if (tid < 2) {
    ustate[n0 + tid] = ut_s[tid];
    ustate[1024 + n0 + tid] = u_s[tid];
  }
}

// ---------------------------------------------------------------- FC + LayerNorm + residual
template <int OM>  // 0 = intra (direct rows), 1 = inter (rows rg = l*1024 + n)
__global__ __launch_bounds__(256) void k_fcln(
    const float* __restrict__ A, const float* __restrict__ Wt,
    const float* __restrict__ bias, const float* __restrict__ gamma,
    const float* __restrict__ beta, const float* __restrict__ resid,
    float* __restrict__ dst, long M0)
{
  __shared__ float As[16][36];
  __shared__ float Bs[16][132];
  __shared__ float red0[32][33];
  __shared__ float red1[32][33];
  __shared__ float mu_s[32];
  __shared__ float rs_s[32];
  const int tid = threadIdx.x;
  const int tx = tid & 31, ty = tid >> 5;
  const long r0l = (long)blockIdx.x * 32;
  const int lr = tid >> 3;
  const int lk2 = (tid & 7) * 2;
  const int bkk = tid >> 4;
  const int bc8 = (tid & 15) * 8;
  float acc[4][4];
#pragma unroll
  for (int i = 0; i < 4; ++i)
#pragma unroll
    for (int j = 0; j < 4; ++j) acc[i][j] = 0.f;

  for (int kt = 0; kt < 8; ++kt) {
    const int k0 = kt * 16;
    const float2 a2 = *reinterpret_cast<const float2*>(&A[(r0l + lr) * 128 + k0 + lk2]);
    As[lk2][lr] = a2.x;
    As[lk2 + 1][lr] = a2.y;
    const float4 w0 = *reinterpret_cast<const float4*>(&Wt[(long)(k0 + bkk) * 128 + bc8]);
    const float4 w1 = *reinterpret_cast<const float4*>(&Wt[(long)(k0 + bkk) * 128 + bc8 + 4]);
    *reinterpret_cast<float4*>(&Bs[bkk][bc8]) = w0;
    *reinterpret_cast<float4*>(&Bs[bkk][bc8 + 4]) = w1;
    __syncthreads();
#pragma unroll
    for (int kk = 0; kk < 16; ++kk) {
      const float4 a4 = *reinterpret_cast<const float4*>(&As[kk][ty * 4]);
      const float4 b4 = *reinterpret_cast<const float4*>(&Bs[kk][tx * 4]);
      const float av[4] = {a4.x, a4.y, a4.z, a4.w};
      const float bv[4] = {b4.x, b4.y, b4.z, b4.w};
#pragma unroll
      for (int i = 0; i < 4; ++i)
#pragma unroll
        for (int j = 0; j < 4; ++j) acc[i][j] = fmaf(av[i], bv[j], acc[i][j]);
    }
    __syncthreads();
  }
  {
    const float4 bb4 = *reinterpret_cast<const float4*>(&bias[tx * 4]);
    const float bv[4] = {bb4.x, bb4.y, bb4.z, bb4.w};
#pragma unroll
    for (int i = 0; i < 4; ++i)
#pragma unroll
      for (int j = 0; j < 4; ++j) acc[i][j] += bv[j];
  }
#pragma unroll
  for (int i = 0; i < 4; ++i) {
    const float s = acc[i][0] + acc[i][1] + acc[i][2] + acc[i][3];
    const float q = acc[i][0] * acc[i][0] + acc[i][1] * acc[i][1] +
                    acc[i][2] * acc[i][2] + acc[i][3] * acc[i][3];
    red0[ty * 4 + i][tx] = s;
    red1[ty * 4 + i][tx] = q;
  }
  __syncthreads();
  if (tid < 32) {
    float s = 0.f, q = 0.f;
#pragma unroll
    for (int j = 0; j < 32; ++j) { s += red0[tid][j]; q += red1[tid][j]; }
    const float mu = s * (1.0f / 128.0f);
    const float var = q * (1.0f / 128.0f) - mu * mu;
    mu_s[tid] = mu;
    rs_s[tid] = 1.0f / sqrtf(var + 1e-8f);
  }
  __syncthreads();
  const float4 g4 = *reinterpret_cast<const float4*>(&gamma[tx * 4]);
  const float4 be4 = *reinterpret_cast<const float4*>(&beta[tx * 4]);
#pragma unroll
  for (int i = 0; i < 4; ++i) {
    const int rloc = ty * 4 + i;
    const long rg = M0 + r0l + rloc;
    long off;
    if (OM == 0) {
      off = rg * 128 + tx * 4;
    } else {
      const int n = (int)(rg & 1023);
      const int l = (int)(rg >> 10);
      off = (((long)(n >> 6) * 200 + l) * 64 + (n & 63)) * 128 + tx * 4;
    }
    const float4 r4 = *reinterpret_cast<const float4*>(&resid[off]);
    const float mu = mu_s[rloc], rs = rs_s[rloc];
    float4 o;
    o.x = (acc[i][0] - mu) * rs * g4.x + be4.x + r4.x;
    o.y = (acc[i][1] - mu) * rs * g4.y + be4.y + r4.y;
    o.z = (acc[i][2] - mu) * rs * g4.z + be4.z + r4.z;
    o.w = (acc[i][3] - mu) * rs * g4.w + be4.w + r4.w;
    *reinterpret_cast<float4*>(&dst[off]) = o;
  }
}

// ============================================================================
extern "C" void kernel_launch(void* const* d_in, const int* in_sizes, int n_in,
                              void* d_out, int out_size, void* d_ws, size_t ws_size,
                              hipStream_t stream)
{
  (void)in_sizes; (void)n_in; (void)out_size;
  const float* x    = (const float*)d_in[0];
  const float* scl  = (const float*)d_in[1];
  const float* Wf   = (const float*)d_in[2];
  const float* Uf   = (const float*)d_in[3];
  const float* bf   = (const float*)d_in[4];
  const float* Wb   = (const float*)d_in[5];
  const float* Ub   = (const float*)d_in[6];
  const float* bb   = (const float*)d_in[7];
  const float* Wfc1 = (const float*)d_in[8];
  const float* bfc1 = (const float*)d_in[9];
  const float* gam1 = (const float*)d_in[10];
  const float* bet1 = (const float*)d_in[11];
  const float* Wi   = (const float*)d_in[12];
  const float* Ui   = (const float*)d_in[13];
  const float* bi   = (const float*)d_in[14];
  const float* Wp   = (const float*)d_in[15];
  const float* bp   = (const float*)d_in[16];
  const float* Wfc2 = (const float*)d_in[17];
  const float* bfc2 = (const float*)d_in[18];
  const float* gam2 = (const float*)d_in[19];
  const float* bet2 = (const float*)d_in[20];

  float* outp  = (float*)d_out;
  float* io    = outp;                         // intra_out lives here
  float* onesp = outp + 26214400L;
  float* gates = outp + 26214400L + 12800L;
  float* ws    = (float*)d_ws;
  const long wsf = (long)(ws_size / sizeof(float));

  k_fill_ones<<<50, 256, 0, stream>>>(onesp, 12800);

  // ---------------- intra pass (seq-chunked) ----------------
  long cnI = (wsf / 32768L) & ~7L;
  if (cnI > 3200) cnI = 3200;
  if (cnI < 8) cnI = 8;
  for (long s0 = 0; s0 < 3200; s0 += cnI) {
    const long cn = (3200 - s0 < cnI) ? (3200 - s0) : cnI;
    float* xwf = ws;
    float* xwb = ws + cn * 12288L;
    float* rnn = ws + cn * 24576L;
    const long M = cn * 64;
    dim3 gg((unsigned)(M / 64), 3);
    k_gemm_xw<MA_X_FWD><<<gg, 256, 0, stream>>>(x, nullptr, Wf, bf, xwf, s0 * 64, 192, 128, 8);
    k_gemm_xw<MA_X_BWD><<<gg, 256, 0, stream>>>(x, nullptr, Wb, bb, xwb, s0 * 64, 192, 128, 8);
    dim3 gr((unsigned)(cn / 8), 2);
    k_gru_intra<<<gr, 256, 0, stream>>>(xwf, xwb, Uf, Ub, rnn, (int)cn);
    k_fcln<0><<<(unsigned)(M / 32), 256, 0, stream>>>(rnn, Wfc1, bfc1, gam1, bet1, x, io, s0 * 64);
  }

  // ---------------- inter pass (t-chunked) ----------------
  const long per_t = 1024L * 384 + 1024L * 128;  // 524288 floats per time step
  const long state_f = 1024L * 128 + 2048L;
  long nt_alloc = (wsf - state_f) / per_t;
  if (nt_alloc > 200) nt_alloc = 200;
  if (nt_alloc < 1) nt_alloc = 1;
  float* xwi    = ws;
  float* rnnI   = ws + nt_alloc * 1024L * 384;
  float* hstate = rnnI + nt_alloc * 1024L * 128;
  float* ustate = hstate + 1024L * 128;

  for (long t0 = 0; t0 < 200; t0 += nt_alloc) {
    const int nt = (int)((200 - t0 < nt_alloc) ? (200 - t0) : nt_alloc);
    dim3 gg((unsigned)(16 * nt), 6);
    k_gemm_xw<MA_INTER><<<gg, 256, 0, stream>>>(io, scl, Wi, bi, xwi, t0 * 1024, 384, 129, 9);
    k_gru_inter2<<<512, 512, 0, stream>>>(xwi, Ui, Wp, bp, rnnI, gates, hstate, ustate,
                                          (int)t0, nt);
    k_fcln<1><<<(unsigned)(32 * nt), 256, 0, stream>>>(rnnI, Wfc2, bfc2, gam2, bet2, io, outp,
                                                       t0 * 1024);
  }
}

// Round 3
// 1884.040 us; speedup vs baseline: 1.1210x; 1.1210x over previous
//
#include <hip/hip_runtime.h>
#include <cmath>

// ============================================================================
// DPRNN block (intra BiGRU + inter Skip-GRU), all fp32.
// NUMERICS: inter skip-GRU binary gate round(sigmoid(h@Wp)) -> keep fp32.
// Round 3: both GRUs rebuilt around register-resident U + readlane broadcast
// (LDS pipe was the bottleneck: ~10K cy/step of redundant ds_read_b128).
// Inter adds u==0 skip (h unchanged -> phases A/B skippable, bit-exact).
// ============================================================================

__device__ __forceinline__ float sigf(float x) { return 1.0f / (1.0f + expf(-x)); }
__device__ __forceinline__ float rlanef(float v, int l) {
  return __uint_as_float(__builtin_amdgcn_readlane(__float_as_uint(v), (unsigned)l));
}

// ---------------------------------------------------------------- fill ones
__global__ __launch_bounds__(256) void k_fill_ones(float* __restrict__ p, int n) {
  int i = blockIdx.x * 256 + threadIdx.x;
  if (i < n) p[i] = 1.0f;
}

// ---------------------------------------------------------------- GEMM (xw precompute)
enum { MA_X_FWD = 0, MA_X_BWD = 1, MA_INTER = 2 };

template <int MODE>
__global__ __launch_bounds__(256) void k_gemm_xw(
    const float* __restrict__ A0, const float* __restrict__ A1,
    const float* __restrict__ Bm, const float* __restrict__ bias,
    float* __restrict__ Cm, long M0, int N, int K, int KT)
{
  __shared__ float As[16][68];
  __shared__ float Bs[16][68];
  const int tid = threadIdx.x;
  const int tx = tid & 15, ty = tid >> 4;
  const long row0g = M0 + (long)blockIdx.x * 64;
  const int col0 = blockIdx.y * 64;
  const int lr = tid >> 2;
  const int lk4 = (tid & 3) * 4;
  const int bk = tid >> 4;
  const int bc4 = (tid & 15) * 4;
  float acc[4][4];
#pragma unroll
  for (int i = 0; i < 4; ++i)
#pragma unroll
    for (int j = 0; j < 4; ++j) acc[i][j] = 0.f;

  for (int kt = 0; kt < KT; ++kt) {
    const int k0 = kt * 16;
    {
      const long rg = row0g + lr;
      float v0, v1, v2, v3;
      if (MODE == MA_X_FWD) {
        const float4 a4 = *reinterpret_cast<const float4*>(&A0[rg * 128 + k0 + lk4]);
        v0 = a4.x; v1 = a4.y; v2 = a4.z; v3 = a4.w;
      } else if (MODE == MA_X_BWD) {
        const long s = rg >> 6; const int t = (int)(rg & 63);
        const float4 a4 =
            *reinterpret_cast<const float4*>(&A0[(s * 64 + (63 - t)) * 128 + k0 + lk4]);
        v0 = a4.x; v1 = a4.y; v2 = a4.z; v3 = a4.w;
      } else {  // MA_INTER: rg = l*1024 + n
        const int n = (int)(rg & 1023);
        const int l = (int)(rg >> 10);
        const long rowc = ((long)(n >> 6) * 200 + l) * 64 + (n & 63);
        const long base = rowc * 128;
        if (kt < 8) {
          const float4 a4 = *reinterpret_cast<const float4*>(&A0[base + k0 + lk4]);
          v0 = a4.x; v1 = a4.y; v2 = a4.z; v3 = a4.w;
        } else {
          v0 = (lk4 == 0) ? A1[rowc] : 0.f;
          v1 = 0.f; v2 = 0.f; v3 = 0.f;
        }
      }
      As[lk4 + 0][lr] = v0;
      As[lk4 + 1][lr] = v1;
      As[lk4 + 2][lr] = v2;
      As[lk4 + 3][lr] = v3;
    }
    {
      const int k = k0 + bk;
      float4 b4 = make_float4(0.f, 0.f, 0.f, 0.f);
      if (k < K) b4 = *reinterpret_cast<const float4*>(&Bm[(long)k * N + col0 + bc4]);
      *reinterpret_cast<float4*>(&Bs[bk][bc4]) = b4;
    }
    __syncthreads();
#pragma unroll
    for (int kk = 0; kk < 16; ++kk) {
      const float4 a4 = *reinterpret_cast<const float4*>(&As[kk][ty * 4]);
      const float4 b4 = *reinterpret_cast<const float4*>(&Bs[kk][tx * 4]);
      const float av[4] = {a4.x, a4.y, a4.z, a4.w};
      const float bv[4] = {b4.x, b4.y, b4.z, b4.w};
#pragma unroll
      for (int i = 0; i < 4; ++i)
#pragma unroll
        for (int j = 0; j < 4; ++j) acc[i][j] = fmaf(av[i], bv[j], acc[i][j]);
    }
    __syncthreads();
  }
  const float4 bi4 = *reinterpret_cast<const float4*>(&bias[col0 + tx * 4]);
  const float bv[4] = {bi4.x, bi4.y, bi4.z, bi4.w};
#pragma unroll
  for (int i = 0; i < 4; ++i) {
    const long rl = (long)blockIdx.x * 64 + ty * 4 + i;
    float4 o;
    o.x = acc[i][0] + bv[0];
    o.y = acc[i][1] + bv[1];
    o.z = acc[i][2] + bv[2];
    o.w = acc[i][3] + bv[3];
    *reinterpret_cast<float4*>(&Cm[rl * (long)N + col0 + tx * 4]) = o;
  }
}

// ---------------------------------------------------------------- intra GRU v2
// 256 thr (4 waves), 4 seqs, one dir per blockIdx.y. U in registers,
// h broadcast via readlane; tiny scalar LDS only for k-split partials.
// zr waves (w=0,1): ks=w (k rows ks*32..+31), cols z=lane, r=64+lane.
// hh waves (w=2,3): ks=w-2, col=lane.
// combine+summer: wave w handles seq w.
__global__ __launch_bounds__(256, 4) void k_gru_intra2(
    const float* __restrict__ xwf, const float* __restrict__ xwb,
    const float* __restrict__ Uf, const float* __restrict__ Ub,
    float* __restrict__ rnn)
{
  const int dir = blockIdx.y;
  const float* __restrict__ xw = dir ? xwb : xwf;
  const float* __restrict__ U  = dir ? Ub : Uf;
  __shared__ float h8[4][64], z8[4][64], rh8[4][64];
  __shared__ float pA[4][2][128];
  __shared__ float pB[4][2][64];
  const int tid = threadIdx.x;
  const int w = tid >> 6, lane = tid & 63;
  const long s0 = (long)blockIdx.x * 4;
  const bool isZR = (w < 2);
  const int ksZ = w;       // valid if isZR
  const int ksH = w - 2;   // valid if !isZR

  float ua[32], ub[32];    // zr: ua=z-col U, ub=r-col U.  hh: ua=hh-col U.
  if (isZR) {
#pragma unroll
    for (int k = 0; k < 32; ++k) {
      ua[k] = U[(ksZ * 32 + k) * 192 + lane];
      ub[k] = U[(ksZ * 32 + k) * 192 + 64 + lane];
    }
  } else {
#pragma unroll
    for (int k = 0; k < 32; ++k)
      ua[k] = U[(ksH * 32 + k) * 192 + 128 + lane];
  }
  h8[w][lane] = 0.f;
  __syncthreads();

  const long xrow0 = (s0 + w) * 64;  // this wave's combiner/summer sequence
  float xa1 = xw[xrow0 * 192 + lane];
  float xa2 = xw[xrow0 * 192 + 64 + lane];
  float xb  = xw[xrow0 * 192 + 128 + lane];

  for (int t = 0; t < 64; ++t) {
    const int tn = (t < 63) ? t + 1 : t;
    const float xa1n = xw[(xrow0 + tn) * 192 + lane];
    const float xa2n = xw[(xrow0 + tn) * 192 + 64 + lane];
    const float xbn  = xw[(xrow0 + tn) * 192 + 128 + lane];
    if (isZR) {
      // hv0: seqs 0,1; hv1: seqs 2,3 (lane>>5 selects seq parity, lane&31 = k)
      const float hv0 = h8[lane >> 5][ksZ * 32 + (lane & 31)];
      const float hv1 = h8[2 + (lane >> 5)][ksZ * 32 + (lane & 31)];
      float az[4], ar[4];
#pragma unroll
      for (int s = 0; s < 4; ++s) { az[s] = 0.f; ar[s] = 0.f; }
#pragma unroll
      for (int s = 0; s < 4; ++s) {
        const float hvr = (s < 2) ? hv0 : hv1;
#pragma unroll
        for (int k = 0; k < 32; ++k) {
          const float hs = rlanef(hvr, ((s & 1) << 5) | k);
          az[s] = fmaf(ua[k], hs, az[s]);
          ar[s] = fmaf(ub[k], hs, ar[s]);
        }
      }
#pragma unroll
      for (int s = 0; s < 4; ++s) {
        pA[s][ksZ][lane] = az[s];
        pA[s][ksZ][64 + lane] = ar[s];
      }
    }
    __syncthreads();  // b1: pA ready
    {  // combine: wave w = seq w
      const float sz = pA[w][0][lane] + pA[w][1][lane] + xa1;
      const float sr = pA[w][0][64 + lane] + pA[w][1][64 + lane] + xa2;
      z8[w][lane] = sigf(sz);
      rh8[w][lane] = sigf(sr) * h8[w][lane];
    }
    __syncthreads();  // b2: z8, rh8 ready
    if (!isZR) {
      const float rv0 = rh8[lane >> 5][ksH * 32 + (lane & 31)];
      const float rv1 = rh8[2 + (lane >> 5)][ksH * 32 + (lane & 31)];
      float ah[4];
#pragma unroll
      for (int s = 0; s < 4; ++s) ah[s] = 0.f;
#pragma unroll
      for (int s = 0; s < 4; ++s) {
        const float rvr = (s < 2) ? rv0 : rv1;
#pragma unroll
        for (int k = 0; k < 32; ++k) {
          const float rs = rlanef(rvr, ((s & 1) << 5) | k);
          ah[s] = fmaf(ua[k], rs, ah[s]);
        }
      }
#pragma unroll
      for (int s = 0; s < 4; ++s) pB[s][ksH][lane] = ah[s];
    }
    __syncthreads();  // b3: pB ready
    {  // summer: wave w = seq w, col = lane
      const float pre = pB[w][0][lane] + pB[w][1][lane] + xb;
      const float hh = tanhf(pre);
      const float z = z8[w][lane];
      const float ho = h8[w][lane];
      const float hn = z * ho + (1.f - z) * hh;
      h8[w][lane] = hn;
      const int tt = dir ? (63 - t) : t;
      rnn[((s0 + w) * 64 + tt) * 128 + dir * 64 + lane] = hn;
    }
    __syncthreads();  // b4: h8 ready for next step
    xa1 = xa1n; xa2 = xa2n; xb = xbn;
  }
}

// ---------------------------------------------------------------- inter skip-GRU v3
// 256 blocks x 1024 thr (16 waves), 4 seqs/block, t-chunked [t0, t0+nt).
// zr waves w=0..7: ks=w (k rows w*16..+15), 4 cols {j*64+lane}, U 64 regs.
// hh waves w=8..15: ks=w-8, 2 cols {lane,64+lane}, U 32 regs.
// combineA: all 16 waves, slot (s=w>>2, c=(w&3)*64+lane).
// summer+gate: waves 0..3 (s=w, cols lane & 64+lane), gate via 64-lane butterfly.
// u==0 skip: if all 4 seqs inactive, phases A/B skipped (h unchanged).
__global__ __launch_bounds__(1024, 4) void k_gru_inter3(
    const float* __restrict__ xw, const float* __restrict__ Ui,
    const float* __restrict__ Wp, const float* __restrict__ bp,
    float* __restrict__ rnn, float* __restrict__ gates,
    float* __restrict__ hstate, float* __restrict__ ustate,
    int t0, int nt)
{
  __shared__ float h4[4][128], z4[4][128], rh4[4][128];
  __shared__ float pA[4][8][256];
  __shared__ float pB[4][8][128];
  __shared__ float uu[4], utt[4];
  const int tid = threadIdx.x;
  const int w = tid >> 6, lane = tid & 63;
  const int n0 = blockIdx.x * 4;
  const bool isZR = (w < 8);

  float ureg[64];  // zr: ureg[j*16+k] j<4; hh: j<2 (manual union -> VGPR budget)
  if (isZR) {
#pragma unroll
    for (int j = 0; j < 4; ++j)
#pragma unroll
      for (int k = 0; k < 16; ++k)
        ureg[j * 16 + k] = Ui[(long)(w * 16 + k) * 384 + j * 64 + lane];
  } else {
    const int ks = w - 8;
#pragma unroll
    for (int j = 0; j < 2; ++j)
#pragma unroll
      for (int k = 0; k < 16; ++k)
        ureg[j * 16 + k] = Ui[(long)(ks * 16 + k) * 384 + 256 + j * 64 + lane];
  }
  if (tid < 512) {
    const int s = tid >> 7, c = tid & 127;
    h4[s][c] = (t0 == 0) ? 0.f : hstate[(long)(n0 + s) * 128 + c];
  }
  if (tid < 4) {
    utt[tid] = (t0 == 0) ? 1.f : ustate[n0 + tid];
    uu[tid]  = (t0 == 0) ? 1.f : ustate[1024 + n0 + tid];
  }
  const float bp0 = bp[0];
  float wprA = 0.f, wprB = 0.f;
  if (w < 4) { wprA = Wp[lane]; wprB = Wp[64 + lane]; }
  __syncthreads();

  // prefetch xw for dl=0
  const int cs = w >> 2;               // combiner seq
  const int cc = (w & 3) * 64 + lane;  // combiner zr col (0..255)
  float xc = xw[(long)(n0 + cs) * 384 + cc];
  float xbA = 0.f, xbB = 0.f;
  if (w < 4) {
    xbA = xw[(long)(n0 + w) * 384 + 256 + lane];
    xbB = xw[(long)(n0 + w) * 384 + 320 + lane];
  }

  for (int dl = 0; dl < nt; ++dl) {
    const float u0g = uu[0], u1g = uu[1], u2g = uu[2], u3g = uu[3];
    const bool act = (u0g + u1g + u2g + u3g) != 0.f;
    const int dn = (dl + 1 < nt) ? dl + 1 : dl;
    const float xcn = xw[((long)dn * 1024 + n0 + cs) * 384 + cc];
    float xbAn = 0.f, xbBn = 0.f;
    if (w < 4) {
      xbAn = xw[((long)dn * 1024 + n0 + w) * 384 + 256 + lane];
      xbBn = xw[((long)dn * 1024 + n0 + w) * 384 + 320 + lane];
    }
    if (act) {
      if (isZR) {  // phase A: z/r partial dots, k-slice w*16..+15
        const float hv = h4[lane >> 4][w * 16 + (lane & 15)];
        float acc[4][4];
#pragma unroll
        for (int j = 0; j < 4; ++j)
#pragma unroll
          for (int s = 0; s < 4; ++s) acc[j][s] = 0.f;
#pragma unroll
        for (int s = 0; s < 4; ++s) {
          const float ug = (s == 0) ? u0g : (s == 1) ? u1g : (s == 2) ? u2g : u3g;
          if (ug != 0.f) {
#pragma unroll
            for (int k = 0; k < 16; ++k) {
              const float hs = rlanef(hv, (s << 4) | k);
              acc[0][s] = fmaf(ureg[k], hs, acc[0][s]);
              acc[1][s] = fmaf(ureg[16 + k], hs, acc[1][s]);
              acc[2][s] = fmaf(ureg[32 + k], hs, acc[2][s]);
              acc[3][s] = fmaf(ureg[48 + k], hs, acc[3][s]);
            }
#pragma unroll
            for (int j = 0; j < 4; ++j) pA[s][w][j * 64 + lane] = acc[j][s];
          }
        }
      }
      __syncthreads();  // b1
      {  // combineA
        const float ugc = uu[cs];
        if (ugc != 0.f) {
          float sum = xc;
#pragma unroll
          for (int ks = 0; ks < 8; ++ks) sum += pA[cs][ks][cc];
          if (cc < 128) z4[cs][cc] = sigf(sum);
          else rh4[cs][cc - 128] = sigf(sum) * h4[cs][cc - 128];
        }
      }
      __syncthreads();  // b2
      if (!isZR) {  // phase B: hh partial dots
        const int ks = w - 8;
        const float rv = rh4[lane >> 4][ks * 16 + (lane & 15)];
        float acc0[4], acc1[4];
#pragma unroll
        for (int s = 0; s < 4; ++s) { acc0[s] = 0.f; acc1[s] = 0.f; }
#pragma unroll
        for (int s = 0; s < 4; ++s) {
          const float ug = (s == 0) ? u0g : (s == 1) ? u1g : (s == 2) ? u2g : u3g;
          if (ug != 0.f) {
#pragma unroll
            for (int k = 0; k < 16; ++k) {
              const float rs = rlanef(rv, (s << 4) | k);
              acc0[s] = fmaf(ureg[k], rs, acc0[s]);
              acc1[s] = fmaf(ureg[16 + k], rs, acc1[s]);
            }
            pB[s][ks][lane] = acc0[s];
            pB[s][ks][64 + lane] = acc1[s];
          }
        }
      }
      __syncthreads();  // b3
    }
    if (w < 4) {  // summer + gate, seq = w
      const float us = uu[w];
      const float hoA = h4[w][lane], hoB = h4[w][64 + lane];
      float hqA, hqB;
      if (us != 0.f) {
        float sA = xbA, sB = xbB;
#pragma unroll
        for (int ks = 0; ks < 8; ++ks) {
          sA += pB[w][ks][lane];
          sB += pB[w][ks][64 + lane];
        }
        const float hhA = tanhf(sA), hhB = tanhf(sB);
        const float zA = z4[w][lane], zB = z4[w][64 + lane];
        hqA = zA * hoA + (1.f - zA) * hhA;
        hqB = zB * hoB + (1.f - zB) * hhB;
        h4[w][lane] = hqA;
        h4[w][64 + lane] = hqB;
      } else {
        hqA = hoA; hqB = hoB;
      }
      rnn[((long)dl * 1024 + n0 + w) * 128 + lane] = hqA;
      rnn[((long)dl * 1024 + n0 + w) * 128 + 64 + lane] = hqB;
      // gate: 64-lane butterfly (same reduce shape as validated rounds)
      float p = hqA * wprA + hqB * wprB;
      p += __shfl_xor(p, 32);
      p += __shfl_xor(p, 16);
      p += __shfl_xor(p, 8);
      p += __shfl_xor(p, 4);
      p += __shfl_xor(p, 2);
      p += __shfl_xor(p, 1);
      const float delta = sigf(p + bp0);
      const float ut = utt[w];
      const float utn = us * delta + (1.f - us) * (ut + fminf(delta, 1.f - ut));
      if (lane == 0) {
        gates[(long)(n0 + w) * 200 + t0 + dl] = us;
        utt[w] = utn;
        uu[w] = rintf(utn);  // half-to-even, matches jnp.round
      }
    }
    __syncthreads();  // b4: h4/uu ready for next step
    xc = xcn; xbA = xbAn; xbB = xbBn;
  }
  if (tid < 512) {
    const int s = tid >> 7, c = tid & 127;
    hstate[(long)(n0 + s) * 128 + c] = h4[s][c];
  }
  if (tid < 4) {
    ustate[n0 + tid] = utt[tid];
    ustate[1024 + n0 + tid] = uu[tid];
  }
}

// ---------------------------------------------------------------- FC + LayerNorm + residual
template <int OM>  // 0 = intra (direct rows), 1 = inter (rows rg = l*1024 + n)
__global__ __launch_bounds__(256) void k_fcln(
    const float* __restrict__ A, const float* __restrict__ Wt,
    const float* __restrict__ bias, const float* __restrict__ gamma,
    const float* __restrict__ beta, const float* __restrict__ resid,
    float* __restrict__ dst, long M0)
{
  __shared__ float As[16][36];
  __shared__ float Bs[16][132];
  __shared__ float red0[32][33];
  __shared__ float red1[32][33];
  __shared__ float mu_s[32];
  __shared__ float rs_s[32];
  const int tid = threadIdx.x;
  const int tx = tid & 31, ty = tid >> 5;
  const long r0l = (long)blockIdx.x * 32;
  const int lr = tid >> 3;
  const int lk2 = (tid & 7) * 2;
  const int bkk = tid >> 4;
  const int bc8 = (tid & 15) * 8;
  float acc[4][4];
#pragma unroll
  for (int i = 0; i < 4; ++i)
#pragma unroll
    for (int j = 0; j < 4; ++j) acc[i][j] = 0.f;

  for (int kt = 0; kt < 8; ++kt) {
    const int k0 = kt * 16;
    const float2 a2 = *reinterpret_cast<const float2*>(&A[(r0l + lr) * 128 + k0 + lk2]);
    As[lk2][lr] = a2.x;
    As[lk2 + 1][lr] = a2.y;
    const float4 w0 = *reinterpret_cast<const float4*>(&Wt[(long)(k0 + bkk) * 128 + bc8]);
    const float4 w1 = *reinterpret_cast<const float4*>(&Wt[(long)(k0 + bkk) * 128 + bc8 + 4]);
    *reinterpret_cast<float4*>(&Bs[bkk][bc8]) = w0;
    *reinterpret_cast<float4*>(&Bs[bkk][bc8 + 4]) = w1;
    __syncthreads();
#pragma unroll
    for (int kk = 0; kk < 16; ++kk) {
      const float4 a4 = *reinterpret_cast<const float4*>(&As[kk][ty * 4]);
      const float4 b4 = *reinterpret_cast<const float4*>(&Bs[kk][tx * 4]);
      const float av[4] = {a4.x, a4.y, a4.z, a4.w};
      const float bv[4] = {b4.x, b4.y, b4.z, b4.w};
#pragma unroll
      for (int i = 0; i < 4; ++i)
#pragma unroll
        for (int j = 0; j < 4; ++j) acc[i][j] = fmaf(av[i], bv[j], acc[i][j]);
    }
    __syncthreads();
  }
  {
    const float4 bb4 = *reinterpret_cast<const float4*>(&bias[tx * 4]);
    const float bv[4] = {bb4.x, bb4.y, bb4.z, bb4.w};
#pragma unroll
    for (int i = 0; i < 4; ++i)
#pragma unroll
      for (int j = 0; j < 4; ++j) acc[i][j] += bv[j];
  }
#pragma unroll
  for (int i = 0; i < 4; ++i) {
    const float s = acc[i][0] + acc[i][1] + acc[i][2] + acc[i][3];
    const float q = acc[i][0] * acc[i][0] + acc[i][1] * acc[i][1] +
                    acc[i][2] * acc[i][2] + acc[i][3] * acc[i][3];
    red0[ty * 4 + i][tx] = s;
    red1[ty * 4 + i][tx] = q;
  }
  __syncthreads();
  if (tid < 32) {
    float s = 0.f, q = 0.f;
#pragma unroll
    for (int j = 0; j < 32; ++j) { s += red0[tid][j]; q += red1[tid][j]; }
    const float mu = s * (1.0f / 128.0f);
    const float var = q * (1.0f / 128.0f) - mu * mu;
    mu_s[tid] = mu;
    rs_s[tid] = 1.0f / sqrtf(var + 1e-8f);
  }
  __syncthreads();
  const float4 g4 = *reinterpret_cast<const float4*>(&gamma[tx * 4]);
  const float4 be4 = *reinterpret_cast<const float4*>(&beta[tx * 4]);
#pragma unroll
  for (int i = 0; i < 4; ++i) {
    const int rloc = ty * 4 + i;
    const long rg = M0 + r0l + rloc;
    long off;
    if (OM == 0) {
      off = rg * 128 + tx * 4;
    } else {
      const int n = (int)(rg & 1023);
      const int l = (int)(rg >> 10);
      off = (((long)(n >> 6) * 200 + l) * 64 + (n & 63)) * 128 + tx * 4;
    }
    const float4 r4 = *reinterpret_cast<const float4*>(&resid[off]);
    const float mu = mu_s[rloc], rs = rs_s[rloc];
    float4 o;
    o.x = (acc[i][0] - mu) * rs * g4.x + be4.x + r4.x;
    o.y = (acc[i][1] - mu) * rs * g4.y + be4.y + r4.y;
    o.z = (acc[i][2] - mu) * rs * g4.z + be4.z + r4.z;
    o.w = (acc[i][3] - mu) * rs * g4.w + be4.w + r4.w;
    *reinterpret_cast<float4*>(&dst[off]) = o;
  }
}

// ============================================================================
extern "C" void kernel_launch(void* const* d_in, const int* in_sizes, int n_in,
                              void* d_out, int out_size, void* d_ws, size_t ws_size,
                              hipStream_t stream)
{
  (void)in_sizes; (void)n_in; (void)out_size;
  const float* x    = (const float*)d_in[0];
  const float* scl  = (const float*)d_in[1];
  const float* Wf   = (const float*)d_in[2];
  const float* Uf   = (const float*)d_in[3];
  const float* bf   = (const float*)d_in[4];
  const float* Wb   = (const float*)d_in[5];
  const float* Ub   = (const float*)d_in[6];
  const float* bb   = (const float*)d_in[7];
  const float* Wfc1 = (const float*)d_in[8];
  const float* bfc1 = (const float*)d_in[9];
  const float* gam1 = (const float*)d_in[10];
  const float* bet1 = (const float*)d_in[11];
  const float* Wi   = (const float*)d_in[12];
  const float* Ui   = (const float*)d_in[13];
  const float* bi   = (const float*)d_in[14];
  const float* Wp   = (const float*)d_in[15];
  const float* bp   = (const float*)d_in[16];
  const float* Wfc2 = (const float*)d_in[17];
  const float* bfc2 = (const float*)d_in[18];
  const float* gam2 = (const float*)d_in[19];
  const float* bet2 = (const float*)d_in[20];

  float* outp  = (float*)d_out;
  float* io    = outp;                         // intra_out lives here
  float* onesp = outp + 26214400L;
  float* gates = outp + 26214400L + 12800L;
  float* ws    = (float*)d_ws;
  const long wsf = (long)(ws_size / sizeof(float));

  k_fill_ones<<<50, 256, 0, stream>>>(onesp, 12800);

  // ---------------- intra pass (seq-chunked) ----------------
  long cnI = (wsf / 32768L) & ~7L;
  if (cnI > 3200) cnI = 3200;
  if (cnI < 8) cnI = 8;
  for (long s0 = 0; s0 < 3200; s0 += cnI) {
    const long cn = (3200 - s0 < cnI) ? (3200 - s0) : cnI;
    float* xwf = ws;
    float* xwb = ws + cn * 12288L;
    float* rnn = ws + cn * 24576L;
    const long M = cn * 64;
    dim3 gg((unsigned)(M / 64), 3);
    k_gemm_xw<MA_X_FWD><<<gg, 256, 0, stream>>>(x, nullptr, Wf, bf, xwf, s0 * 64, 192, 128, 8);
    k_gemm_xw<MA_X_BWD><<<gg, 256, 0, stream>>>(x, nullptr, Wb, bb, xwb, s0 * 64, 192, 128, 8);
    dim3 gr((unsigned)(cn / 4), 2);
    k_gru_intra2<<<gr, 256, 0, stream>>>(xwf, xwb, Uf, Ub, rnn);
    k_fcln<0><<<(unsigned)(M / 32), 256, 0, stream>>>(rnn, Wfc1, bfc1, gam1, bet1, x, io, s0 * 64);
  }

  // ---------------- inter pass (t-chunked) ----------------
  const long per_t = 1024L * 384 + 1024L * 128;  // floats per time step
  const long state_f = 1024L * 128 + 3072L;
  long nt_alloc = (wsf - state_f) / per_t;
  if (nt_alloc > 200) nt_alloc = 200;
  if (nt_alloc < 1) nt_alloc = 1;
  float* xwi    = ws;
  float* rnnI   = ws + nt_alloc * 1024L * 384;
  float* hstate = rnnI + nt_alloc * 1024L * 128;
  float* ustate = hstate + 1024L * 128;

  for (long t0 = 0; t0 < 200; t0 += nt_alloc) {
    const int nt = (int)((200 - t0 < nt_alloc) ? (200 - t0) : nt_alloc);
    dim3 gg((unsigned)(16 * nt), 6);
    k_gemm_xw<MA_INTER><<<gg, 256, 0, stream>>>(io, scl, Wi, bi, xwi, t0 * 1024, 384, 129, 9);
    k_gru_inter3<<<256, 1024, 0, stream>>>(xwi, Ui, Wp, bp, rnnI, gates, hstate, ustate,
                                           (int)t0, nt);
    k_fcln<1><<<(unsigned)(32 * nt), 256, 0, stream>>>(rnnI, Wfc2, bfc2, gam2, bet2, io, outp,
                                                       t0 * 1024);
  }
}

// Round 4
// 1882.569 us; speedup vs baseline: 1.1219x; 1.0008x over previous
//
#include <hip/hip_runtime.h>
#include <cmath>

// ============================================================================
// DPRNN block (intra BiGRU + inter Skip-GRU), all fp32.
// NUMERICS: inter skip-GRU binary gate round(sigmoid(h@Wp)) -> keep fp32.
// Round 4: U matrices in TRUE registers via ext_vector_type(16) (rounds 1-3
// all silently spilled float[64] U arrays to scratch: WRITE_SIZE showed the
// 67MB spill store; VGPR_Count=64 < the 64-float array). All weight indexing
// is compile-time constant through template<int SB> MAC helpers.
// ============================================================================

typedef float f32x16 __attribute__((ext_vector_type(16)));

__device__ __forceinline__ float sigf(float x) { return 1.0f / (1.0f + expf(-x)); }
__device__ __forceinline__ float rlanef(float v, int l) {
  return __uint_as_float(__builtin_amdgcn_readlane(__float_as_uint(v), (unsigned)l));
}

// 16-k MAC over 4 column groups (inter zr waves)
template <int SB>
__device__ __forceinline__ void mac4(const f32x16& u0, const f32x16& u1,
                                     const f32x16& u2, const f32x16& u3, float hv,
                                     float& a0, float& a1, float& a2, float& a3) {
#pragma unroll
  for (int k = 0; k < 16; ++k) {
    const float hs = rlanef(hv, SB + k);
    a0 = fmaf(u0[k], hs, a0);
    a1 = fmaf(u1[k], hs, a1);
    a2 = fmaf(u2[k], hs, a2);
    a3 = fmaf(u3[k], hs, a3);
  }
}

// 16-k MAC over 2 column groups (inter hh waves)
template <int SB>
__device__ __forceinline__ void mac2(const f32x16& u0, const f32x16& u1, float hv,
                                     float& a0, float& a1) {
#pragma unroll
  for (int k = 0; k < 16; ++k) {
    const float hs = rlanef(hv, SB + k);
    a0 = fmaf(u0[k], hs, a0);
    a1 = fmaf(u1[k], hs, a1);
  }
}

// 32-k MAC over 2 column groups (intra zr waves)
template <int SB>
__device__ __forceinline__ void macI2(const f32x16& alo, const f32x16& ahi,
                                      const f32x16& blo, const f32x16& bhi, float hv,
                                      float& az, float& ar) {
#pragma unroll
  for (int k = 0; k < 16; ++k) {
    const float hs = rlanef(hv, SB + k);
    az = fmaf(alo[k], hs, az);
    ar = fmaf(blo[k], hs, ar);
  }
#pragma unroll
  for (int k = 0; k < 16; ++k) {
    const float hs = rlanef(hv, SB + 16 + k);
    az = fmaf(ahi[k], hs, az);
    ar = fmaf(bhi[k], hs, ar);
  }
}

// 32-k MAC over 1 column group (intra hh waves)
template <int SB>
__device__ __forceinline__ void macI1(const f32x16& alo, const f32x16& ahi, float hv,
                                      float& ah) {
#pragma unroll
  for (int k = 0; k < 16; ++k) ah = fmaf(alo[k], rlanef(hv, SB + k), ah);
#pragma unroll
  for (int k = 0; k < 16; ++k) ah = fmaf(ahi[k], rlanef(hv, SB + 16 + k), ah);
}

// ---------------------------------------------------------------- fill ones
__global__ __launch_bounds__(256) void k_fill_ones(float* __restrict__ p, int n) {
  int i = blockIdx.x * 256 + threadIdx.x;
  if (i < n) p[i] = 1.0f;
}

// ---------------------------------------------------------------- GEMM (xw precompute)
enum { MA_X_FWD = 0, MA_X_BWD = 1, MA_INTER = 2 };

template <int MODE>
__global__ __launch_bounds__(256) void k_gemm_xw(
    const float* __restrict__ A0, const float* __restrict__ A1,
    const float* __restrict__ Bm, const float* __restrict__ bias,
    float* __restrict__ Cm, long M0, int N, int K, int KT)
{
  __shared__ float As[16][68];
  __shared__ float Bs[16][68];
  const int tid = threadIdx.x;
  const int tx = tid & 15, ty = tid >> 4;
  const long row0g = M0 + (long)blockIdx.x * 64;
  const int col0 = blockIdx.y * 64;
  const int lr = tid >> 2;
  const int lk4 = (tid & 3) * 4;
  const int bk = tid >> 4;
  const int bc4 = (tid & 15) * 4;
  float acc[4][4];
#pragma unroll
  for (int i = 0; i < 4; ++i)
#pragma unroll
    for (int j = 0; j < 4; ++j) acc[i][j] = 0.f;

  for (int kt = 0; kt < KT; ++kt) {
    const int k0 = kt * 16;
    {
      const long rg = row0g + lr;
      float v0, v1, v2, v3;
      if (MODE == MA_X_FWD) {
        const float4 a4 = *reinterpret_cast<const float4*>(&A0[rg * 128 + k0 + lk4]);
        v0 = a4.x; v1 = a4.y; v2 = a4.z; v3 = a4.w;
      } else if (MODE == MA_X_BWD) {
        const long s = rg >> 6; const int t = (int)(rg & 63);
        const float4 a4 =
            *reinterpret_cast<const float4*>(&A0[(s * 64 + (63 - t)) * 128 + k0 + lk4]);
        v0 = a4.x; v1 = a4.y; v2 = a4.z; v3 = a4.w;
      } else {  // MA_INTER: rg = l*1024 + n
        const int n = (int)(rg & 1023);
        const int l = (int)(rg >> 10);
        const long rowc = ((long)(n >> 6) * 200 + l) * 64 + (n & 63);
        const long base = rowc * 128;
        if (kt < 8) {
          const float4 a4 = *reinterpret_cast<const float4*>(&A0[base + k0 + lk4]);
          v0 = a4.x; v1 = a4.y; v2 = a4.z; v3 = a4.w;
        } else {
          v0 = (lk4 == 0) ? A1[rowc] : 0.f;
          v1 = 0.f; v2 = 0.f; v3 = 0.f;
        }
      }
      As[lk4 + 0][lr] = v0;
      As[lk4 + 1][lr] = v1;
      As[lk4 + 2][lr] = v2;
      As[lk4 + 3][lr] = v3;
    }
    {
      const int k = k0 + bk;
      float4 b4 = make_float4(0.f, 0.f, 0.f, 0.f);
      if (k < K) b4 = *reinterpret_cast<const float4*>(&Bm[(long)k * N + col0 + bc4]);
      *reinterpret_cast<float4*>(&Bs[bk][bc4]) = b4;
    }
    __syncthreads();
#pragma unroll
    for (int kk = 0; kk < 16; ++kk) {
      const float4 a4 = *reinterpret_cast<const float4*>(&As[kk][ty * 4]);
      const float4 b4 = *reinterpret_cast<const float4*>(&Bs[kk][tx * 4]);
      const float av[4] = {a4.x, a4.y, a4.z, a4.w};
      const float bv[4] = {b4.x, b4.y, b4.z, b4.w};
#pragma unroll
      for (int i = 0; i < 4; ++i)
#pragma unroll
        for (int j = 0; j < 4; ++j) acc[i][j] = fmaf(av[i], bv[j], acc[i][j]);
    }
    __syncthreads();
  }
  const float4 bi4 = *reinterpret_cast<const float4*>(&bias[col0 + tx * 4]);
  const float bv[4] = {bi4.x, bi4.y, bi4.z, bi4.w};
#pragma unroll
  for (int i = 0; i < 4; ++i) {
    const long rl = (long)blockIdx.x * 64 + ty * 4 + i;
    float4 o;
    o.x = acc[i][0] + bv[0];
    o.y = acc[i][1] + bv[1];
    o.z = acc[i][2] + bv[2];
    o.w = acc[i][3] + bv[3];
    *reinterpret_cast<float4*>(&Cm[rl * (long)N + col0 + tx * 4]) = o;
  }
}

// ---------------------------------------------------------------- intra GRU v3
// 256 thr (4 waves), 4 seqs, one dir per blockIdx.y. U in ext_vector registers.
// zr waves (w=0,1): k-slice w*32..+31, cols z=lane, r=64+lane.
// hh waves (w=2,3): k-slice (w-2)*32..+31, col=lane.
__global__ __launch_bounds__(256, 4) void k_gru_intra3(
    const float* __restrict__ xwf, const float* __restrict__ xwb,
    const float* __restrict__ Uf, const float* __restrict__ Ub,
    float* __restrict__ rnn)
{
  const int dir = blockIdx.y;
  const float* __restrict__ xw = dir ? xwb : xwf;
  const float* __restrict__ U  = dir ? Ub : Uf;
  __shared__ float h8[4][64], z8[4][64], rh8[4][64];
  __shared__ float pA[4][2][128];
  __shared__ float pB[4][2][64];
  const int tid = threadIdx.x;
  const int w = tid >> 6, lane = tid & 63;
  const long s0 = (long)blockIdx.x * 4;
  const bool isZR = (w < 2);

  f32x16 ualo, uahi, ublo, ubhi;  // zr: z-col (a) + r-col (b); hh: a only
  if (isZR) {
#pragma unroll
    for (int k = 0; k < 16; ++k) {
      const int r0 = (w * 32 + k) * 192, r1 = (w * 32 + 16 + k) * 192;
      ualo[k] = U[r0 + lane];
      uahi[k] = U[r1 + lane];
      ublo[k] = U[r0 + 64 + lane];
      ubhi[k] = U[r1 + 64 + lane];
    }
  } else {
    const int ks = w - 2;
#pragma unroll
    for (int k = 0; k < 16; ++k) {
      ualo[k] = U[(ks * 32 + k) * 192 + 128 + lane];
      uahi[k] = U[(ks * 32 + 16 + k) * 192 + 128 + lane];
    }
  }
  h8[w][lane] = 0.f;
  __syncthreads();

  const long xrow0 = (s0 + w) * 64;  // this wave's combiner/summer sequence
  float xa1 = xw[xrow0 * 192 + lane];
  float xa2 = xw[xrow0 * 192 + 64 + lane];
  float xb  = xw[xrow0 * 192 + 128 + lane];

  for (int t = 0; t < 64; ++t) {
    const int tn = (t < 63) ? t + 1 : t;
    const float xa1n = xw[(xrow0 + tn) * 192 + lane];
    const float xa2n = xw[(xrow0 + tn) * 192 + 64 + lane];
    const float xbn  = xw[(xrow0 + tn) * 192 + 128 + lane];
    if (isZR) {
      const float hv0 = h8[lane >> 5][w * 32 + (lane & 31)];      // seqs 0,1
      const float hv1 = h8[2 + (lane >> 5)][w * 32 + (lane & 31)];  // seqs 2,3
      float az0 = 0.f, ar0 = 0.f, az1 = 0.f, ar1 = 0.f;
      float az2 = 0.f, ar2 = 0.f, az3 = 0.f, ar3 = 0.f;
      macI2<0>(ualo, uahi, ublo, ubhi, hv0, az0, ar0);
      macI2<32>(ualo, uahi, ublo, ubhi, hv0, az1, ar1);
      macI2<0>(ualo, uahi, ublo, ubhi, hv1, az2, ar2);
      macI2<32>(ualo, uahi, ublo, ubhi, hv1, az3, ar3);
      pA[0][w][lane] = az0; pA[0][w][64 + lane] = ar0;
      pA[1][w][lane] = az1; pA[1][w][64 + lane] = ar1;
      pA[2][w][lane] = az2; pA[2][w][64 + lane] = ar2;
      pA[3][w][lane] = az3; pA[3][w][64 + lane] = ar3;
    }
    __syncthreads();  // b1: pA ready
    {  // combine: wave w = seq w
      const float sz = pA[w][0][lane] + pA[w][1][lane] + xa1;
      const float sr = pA[w][0][64 + lane] + pA[w][1][64 + lane] + xa2;
      z8[w][lane] = sigf(sz);
      rh8[w][lane] = sigf(sr) * h8[w][lane];
    }
    __syncthreads();  // b2: z8, rh8 ready
    if (!isZR) {
      const int ks = w - 2;
      const float rv0 = rh8[lane >> 5][ks * 32 + (lane & 31)];
      const float rv1 = rh8[2 + (lane >> 5)][ks * 32 + (lane & 31)];
      float a0 = 0.f, a1 = 0.f, a2 = 0.f, a3 = 0.f;
      macI1<0>(ualo, uahi, rv0, a0);
      macI1<32>(ualo, uahi, rv0, a1);
      macI1<0>(ualo, uahi, rv1, a2);
      macI1<32>(ualo, uahi, rv1, a3);
      pB[0][ks][lane] = a0;
      pB[1][ks][lane] = a1;
      pB[2][ks][lane] = a2;
      pB[3][ks][lane] = a3;
    }
    __syncthreads();  // b3: pB ready
    {  // summer: wave w = seq w, col = lane
      const float pre = pB[w][0][lane] + pB[w][1][lane] + xb;
      const float hh = tanhf(pre);
      const float z = z8[w][lane];
      const float ho = h8[w][lane];
      const float hn = z * ho + (1.f - z) * hh;
      h8[w][lane] = hn;
      const int tt = dir ? (63 - t) : t;
      rnn[((s0 + w) * 64 + tt) * 128 + dir * 64 + lane] = hn;
    }
    __syncthreads();  // b4: h8 ready for next step
    xa1 = xa1n; xa2 = xa2n; xb = xbn;
  }
}

// ---------------------------------------------------------------- inter skip-GRU v4
// 256 blocks x 1024 thr (16 waves), 4 seqs/block, t-chunked [t0, t0+nt).
// zr waves w=0..7: k-slice w*16..+15, cols {j*64+lane} j=0..3, U = 4x f32x16.
// hh waves w=8..15: k-slice (w-8)*16..+15, cols {lane, 64+lane}, U = 2x f32x16
// (reusing uA0/uA1 so register pressure tops at 64 U-VGPRs either way).
// u==0 skip: if all 4 seqs inactive, phases A/B skipped (h unchanged).
__global__ __launch_bounds__(1024, 4) void k_gru_inter4(
    const float* __restrict__ xw, const float* __restrict__ Ui,
    const float* __restrict__ Wp, const float* __restrict__ bp,
    float* __restrict__ rnn, float* __restrict__ gates,
    float* __restrict__ hstate, float* __restrict__ ustate,
    int t0, int nt)
{
  __shared__ float h4[4][128], z4[4][128], rh4[4][128];
  __shared__ float pA[4][8][256];
  __shared__ float pB[4][8][128];
  __shared__ float uu[4], utt[4];
  const int tid = threadIdx.x;
  const int w = tid >> 6, lane = tid & 63;
  const int n0 = blockIdx.x * 4;
  const bool isZR = (w < 8);

  f32x16 uA0, uA1, uA2, uA3;
  if (isZR) {
#pragma unroll
    for (int k = 0; k < 16; ++k) {
      const long r = (long)(w * 16 + k) * 384;
      uA0[k] = Ui[r + lane];
      uA1[k] = Ui[r + 64 + lane];
      uA2[k] = Ui[r + 128 + lane];
      uA3[k] = Ui[r + 192 + lane];
    }
  } else {
    const int ks = w - 8;
#pragma unroll
    for (int k = 0; k < 16; ++k) {
      const long r = (long)(ks * 16 + k) * 384 + 256;
      uA0[k] = Ui[r + lane];
      uA1[k] = Ui[r + 64 + lane];
    }
  }
  if (tid < 512) {
    const int s = tid >> 7, c = tid & 127;
    h4[s][c] = (t0 == 0) ? 0.f : hstate[(long)(n0 + s) * 128 + c];
  }
  if (tid < 4) {
    utt[tid] = (t0 == 0) ? 1.f : ustate[n0 + tid];
    uu[tid]  = (t0 == 0) ? 1.f : ustate[1024 + n0 + tid];
  }
  const float bp0 = bp[0];
  float wprA = 0.f, wprB = 0.f;
  if (w < 4) { wprA = Wp[lane]; wprB = Wp[64 + lane]; }
  __syncthreads();

  // prefetch xw for dl=0
  const int cs = w >> 2;               // combiner seq
  const int cc = (w & 3) * 64 + lane;  // combiner zr col (0..255)
  float xc = xw[(long)(n0 + cs) * 384 + cc];
  float xbA = 0.f, xbB = 0.f;
  if (w < 4) {
    xbA = xw[(long)(n0 + w) * 384 + 256 + lane];
    xbB = xw[(long)(n0 + w) * 384 + 320 + lane];
  }

  for (int dl = 0; dl < nt; ++dl) {
    const float u0g = uu[0], u1g = uu[1], u2g = uu[2], u3g = uu[3];
    const bool act = (u0g + u1g + u2g + u3g) != 0.f;
    const int dn = (dl + 1 < nt) ? dl + 1 : dl;
    const float xcn = xw[((long)dn * 1024 + n0 + cs) * 384 + cc];
    float xbAn = 0.f, xbBn = 0.f;
    if (w < 4) {
      xbAn = xw[((long)dn * 1024 + n0 + w) * 384 + 256 + lane];
      xbBn = xw[((long)dn * 1024 + n0 + w) * 384 + 320 + lane];
    }
    if (act) {
      if (isZR) {  // phase A: z/r partial dots, k-slice w*16..+15
        const float hv = h4[lane >> 4][w * 16 + (lane & 15)];
        if (u0g != 0.f) {
          float a0 = 0.f, a1 = 0.f, a2 = 0.f, a3 = 0.f;
          mac4<0>(uA0, uA1, uA2, uA3, hv, a0, a1, a2, a3);
          pA[0][w][lane] = a0; pA[0][w][64 + lane] = a1;
          pA[0][w][128 + lane] = a2; pA[0][w][192 + lane] = a3;
        }
        if (u1g != 0.f) {
          float a0 = 0.f, a1 = 0.f, a2 = 0.f, a3 = 0.f;
          mac4<16>(uA0, uA1, uA2, uA3, hv, a0, a1, a2, a3);
          pA[1][w][lane] = a0; pA[1][w][64 + lane] = a1;
          pA[1][w][128 + lane] = a2; pA[1][w][192 + lane] = a3;
        }
        if (u2g != 0.f) {
          float a0 = 0.f, a1 = 0.f, a2 = 0.f, a3 = 0.f;
          mac4<32>(uA0, uA1, uA2, uA3, hv, a0, a1, a2, a3);
          pA[2][w][lane] = a0; pA[2][w][64 + lane] = a1;
          pA[2][w][128 + lane] = a2; pA[2][w][192 + lane] = a3;
        }
        if (u3g != 0.f) {
          float a0 = 0.f, a1 = 0.f, a2 = 0.f, a3 = 0.f;
          mac4<48>(uA0, uA1, uA2, uA3, hv, a0, a1, a2, a3);
          pA[3][w][lane] = a0; pA[3][w][64 + lane] = a1;
          pA[3][w][128 + lane] = a2; pA[3][w][192 + lane] = a3;
        }
      }
      __syncthreads();  // b1
      {  // combineA
        if (uu[cs] != 0.f) {
          float sum = xc;
#pragma unroll
          for (int ks = 0; ks < 8; ++ks) sum += pA[cs][ks][cc];
          if (cc < 128) z4[cs][cc] = sigf(sum);
          else rh4[cs][cc - 128] = sigf(sum) * h4[cs][cc - 128];
        }
      }
      __syncthreads();  // b2
      if (!isZR) {  // phase B: hh partial dots
        const int ks = w - 8;
        const float rv = rh4[lane >> 4][ks * 16 + (lane & 15)];
        if (u0g != 0.f) {
          float b0 = 0.f, b1 = 0.f;
          mac2<0>(uA0, uA1, rv, b0, b1);
          pB[0][ks][lane] = b0; pB[0][ks][64 + lane] = b1;
        }
        if (u1g != 0.f) {
          float b0 = 0.f, b1 = 0.f;
          mac2<16>(uA0, uA1, rv, b0, b1);
          pB[1][ks][lane] = b0; pB[1][ks][64 + lane] = b1;
        }
        if (u2g != 0.f) {
          float b0 = 0.f, b1 = 0.f;
          mac2<32>(uA0, uA1, rv, b0, b1);
          pB[2][ks][lane] = b0; pB[2][ks][64 + lane] = b1;
        }
        if (u3g != 0.f) {
          float b0 = 0.f, b1 = 0.f;
          mac2<48>(uA0, uA1, rv, b0, b1);
          pB[3][ks][lane] = b0; pB[3][ks][64 + lane] = b1;
        }
      }
      __syncthreads();  // b3
    }
    if (w < 4) {  // summer + gate, seq = w
      const float us = uu[w];
      const float hoA = h4[w][lane], hoB = h4[w][64 + lane];
      float hqA, hqB;
      if (us != 0.f) {
        float sA = xbA, sB = xbB;
#pragma unroll
        for (int ks = 0; ks < 8; ++ks) {
          sA += pB[w][ks][lane];
          sB += pB[w][ks][64 + lane];
        }
        const float hhA = tanhf(sA), hhB = tanhf(sB);
        const float zA = z4[w][lane], zB = z4[w][64 + lane];
        hqA = zA * hoA + (1.f - zA) * hhA;
        hqB = zB * hoB + (1.f - zB) * hhB;
        h4[w][lane] = hqA;
        h4[w][64 + lane] = hqB;
      } else {
        hqA = hoA; hqB = hoB;
      }
      rnn[((long)dl * 1024 + n0 + w) * 128 + lane] = hqA;
      rnn[((long)dl * 1024 + n0 + w) * 128 + 64 + lane] = hqB;
      // gate: 64-lane butterfly
      float p = hqA * wprA + hqB * wprB;
      p += __shfl_xor(p, 32);
      p += __shfl_xor(p, 16);
      p += __shfl_xor(p, 8);
      p += __shfl_xor(p, 4);
      p += __shfl_xor(p, 2);
      p += __shfl_xor(p, 1);
      const float delta = sigf(p + bp0);
      const float ut = utt[w];
      const float utn = us * delta + (1.f - us) * (ut + fminf(delta, 1.f - ut));
      if (lane == 0) {
        gates[(long)(n0 + w) * 200 + t0 + dl] = us;
        utt[w] = utn;
        uu[w] = rintf(utn);  // half-to-even, matches jnp.round
      }
    }
    __syncthreads();  // b4: h4/uu ready for next step
    xc = xcn; xbA = xbAn; xbB = xbBn;
  }
  if (tid < 512) {
    const int s = tid >> 7, c = tid & 127;
    hstate[(long)(n0 + s) * 128 + c] = h4[s][c];
  }
  if (tid < 4) {
    ustate[n0 + tid] = utt[tid];
    ustate[1024 + n0 + tid] = uu[tid];
  }
}

// ---------------------------------------------------------------- FC + LayerNorm + residual
template <int OM>  // 0 = intra (direct rows), 1 = inter (rows rg = l*1024 + n)
__global__ __launch_bounds__(256) void k_fcln(
    const float* __restrict__ A, const float* __restrict__ Wt,
    const float* __restrict__ bias, const float* __restrict__ gamma,
    const float* __restrict__ beta, const float* __restrict__ resid,
    float* __restrict__ dst, long M0)
{
  __shared__ float As[16][36];
  __shared__ float Bs[16][132];
  __shared__ float red0[32][33];
  __shared__ float red1[32][33];
  __shared__ float mu_s[32];
  __shared__ float rs_s[32];
  const int tid = threadIdx.x;
  const int tx = tid & 31, ty = tid >> 5;
  const long r0l = (long)blockIdx.x * 32;
  const int lr = tid >> 3;
  const int lk2 = (tid & 7) * 2;
  const int bkk = tid >> 4;
  const int bc8 = (tid & 15) * 8;
  float acc[4][4];
#pragma unroll
  for (int i = 0; i < 4; ++i)
#pragma unroll
    for (int j = 0; j < 4; ++j) acc[i][j] = 0.f;

  for (int kt = 0; kt < 8; ++kt) {
    const int k0 = kt * 16;
    const float2 a2 = *reinterpret_cast<const float2*>(&A[(r0l + lr) * 128 + k0 + lk2]);
    As[lk2][lr] = a2.x;
    As[lk2 + 1][lr] = a2.y;
    const float4 w0 = *reinterpret_cast<const float4*>(&Wt[(long)(k0 + bkk) * 128 + bc8]);
    const float4 w1 = *reinterpret_cast<const float4*>(&Wt[(long)(k0 + bkk) * 128 + bc8 + 4]);
    *reinterpret_cast<float4*>(&Bs[bkk][bc8]) = w0;
    *reinterpret_cast<float4*>(&Bs[bkk][bc8 + 4]) = w1;
    __syncthreads();
#pragma unroll
    for (int kk = 0; kk < 16; ++kk) {
      const float4 a4 = *reinterpret_cast<const float4*>(&As[kk][ty * 4]);
      const float4 b4 = *reinterpret_cast<const float4*>(&Bs[kk][tx * 4]);
      const float av[4] = {a4.x, a4.y, a4.z, a4.w};
      const float bv[4] = {b4.x, b4.y, b4.z, b4.w};
#pragma unroll
      for (int i = 0; i < 4; ++i)
#pragma unroll
        for (int j = 0; j < 4; ++j) acc[i][j] = fmaf(av[i], bv[j], acc[i][j]);
    }
    __syncthreads();
  }
  {
    const float4 bb4 = *reinterpret_cast<const float4*>(&bias[tx * 4]);
    const float bv[4] = {bb4.x, bb4.y, bb4.z, bb4.w};
#pragma unroll
    for (int i = 0; i < 4; ++i)
#pragma unroll
      for (int j = 0; j < 4; ++j) acc[i][j] += bv[j];
  }
#pragma unroll
  for (int i = 0; i < 4; ++i) {
    const float s = acc[i][0] + acc[i][1] + acc[i][2] + acc[i][3];
    const float q = acc[i][0] * acc[i][0] + acc[i][1] * acc[i][1] +
                    acc[i][2] * acc[i][2] + acc[i][3] * acc[i][3];
    red0[ty * 4 + i][tx] = s;
    red1[ty * 4 + i][tx] = q;
  }
  __syncthreads();
  if (tid < 32) {
    float s = 0.f, q = 0.f;
#pragma unroll
    for (int j = 0; j < 32; ++j) { s += red0[tid][j]; q += red1[tid][j]; }
    const float mu = s * (1.0f / 128.0f);
    const float var = q * (1.0f / 128.0f) - mu * mu;
    mu_s[tid] = mu;
    rs_s[tid] = 1.0f / sqrtf(var + 1e-8f);
  }
  __syncthreads();
  const float4 g4 = *reinterpret_cast<const float4*>(&gamma[tx * 4]);
  const float4 be4 = *reinterpret_cast<const float4*>(&beta[tx * 4]);
#pragma unroll
  for (int i = 0; i < 4; ++i) {
    const int rloc = ty * 4 + i;
    const long rg = M0 + r0l + rloc;
    long off;
    if (OM == 0) {
      off = rg * 128 + tx * 4;
    } else {
      const int n = (int)(rg & 1023);
      const int l = (int)(rg >> 10);
      off = (((long)(n >> 6) * 200 + l) * 64 + (n & 63)) * 128 + tx * 4;
    }
    const float4 r4 = *reinterpret_cast<const float4*>(&resid[off]);
    const float mu = mu_s[rloc], rs = rs_s[rloc];
    float4 o;
    o.x = (acc[i][0] - mu) * rs * g4.x + be4.x + r4.x;
    o.y = (acc[i][1] - mu) * rs * g4.y + be4.y + r4.y;
    o.z = (acc[i][2] - mu) * rs * g4.z + be4.z + r4.z;
    o.w = (acc[i][3] - mu) * rs * g4.w + be4.w + r4.w;
    *reinterpret_cast<float4*>(&dst[off]) = o;
  }
}

// ============================================================================
extern "C" void kernel_launch(void* const* d_in, const int* in_sizes, int n_in,
                              void* d_out, int out_size, void* d_ws, size_t ws_size,
                              hipStream_t stream)
{
  (void)in_sizes; (void)n_in; (void)out_size;
  const float* x    = (const float*)d_in[0];
  const float* scl  = (const float*)d_in[1];
  const float* Wf   = (const float*)d_in[2];
  const float* Uf   = (const float*)d_in[3];
  const float* bf   = (const float*)d_in[4];
  const float* Wb   = (const float*)d_in[5];
  const float* Ub   = (const float*)d_in[6];
  const float* bb   = (const float*)d_in[7];
  const float* Wfc1 = (const float*)d_in[8];
  const float* bfc1 = (const float*)d_in[9];
  const float* gam1 = (const float*)d_in[10];
  const float* bet1 = (const float*)d_in[11];
  const float* Wi   = (const float*)d_in[12];
  const float* Ui   = (const float*)d_in[13];
  const float* bi   = (const float*)d_in[14];
  const float* Wp   = (const float*)d_in[15];
  const float* bp   = (const float*)d_in[16];
  const float* Wfc2 = (const float*)d_in[17];
  const float* bfc2 = (const float*)d_in[18];
  const float* gam2 = (const float*)d_in[19];
  const float* bet2 = (const float*)d_in[20];

  float* outp  = (float*)d_out;
  float* io    = outp;                         // intra_out lives here
  float* onesp = outp + 26214400L;
  float* gates = outp + 26214400L + 12800L;
  float* ws    = (float*)d_ws;
  const long wsf = (long)(ws_size / sizeof(float));

  k_fill_ones<<<50, 256, 0, stream>>>(onesp, 12800);

  // ---------------- intra pass (seq-chunked) ----------------
  long cnI = (wsf / 32768L) & ~7L;
  if (cnI > 3200) cnI = 3200;
  if (cnI < 8) cnI = 8;
  for (long s0 = 0; s0 < 3200; s0 += cnI) {
    const long cn = (3200 - s0 < cnI) ? (3200 - s0) : cnI;
    float* xwf = ws;
    float* xwb = ws + cn * 12288L;
    float* rnn = ws + cn * 24576L;
    const long M = cn * 64;
    dim3 gg((unsigned)(M / 64), 3);
    k_gemm_xw<MA_X_FWD><<<gg, 256, 0, stream>>>(x, nullptr, Wf, bf, xwf, s0 * 64, 192, 128, 8);
    k_gemm_xw<MA_X_BWD><<<gg, 256, 0, stream>>>(x, nullptr, Wb, bb, xwb, s0 * 64, 192, 128, 8);
    dim3 gr((unsigned)(cn / 4), 2);
    k_gru_intra3<<<gr, 256, 0, stream>>>(xwf, xwb, Uf, Ub, rnn);
    k_fcln<0><<<(unsigned)(M / 32), 256, 0, stream>>>(rnn, Wfc1, bfc1, gam1, bet1, x, io, s0 * 64);
  }

  // ---------------- inter pass (t-chunked) ----------------
  const long per_t = 1024L * 384 + 1024L * 128;  // floats per time step
  const long state_f = 1024L * 128 + 3072L;
  long nt_alloc = (wsf - state_f) / per_t;
  if (nt_alloc > 200) nt_alloc = 200;
  if (nt_alloc < 1) nt_alloc = 1;
  float* xwi    = ws;
  float* rnnI   = ws + nt_alloc * 1024L * 384;
  float* hstate = rnnI + nt_alloc * 1024L * 128;
  float* ustate = hstate + 1024L * 128;

  for (long t0 = 0; t0 < 200; t0 += nt_alloc) {
    const int nt = (int)((200 - t0 < nt_alloc) ? (200 - t0) : nt_alloc);
    dim3 gg((unsigned)(16 * nt), 6);
    k_gemm_xw<MA_INTER><<<gg, 256, 0, stream>>>(io, scl, Wi, bi, xwi, t0 * 1024, 384, 129, 9);
    k_gru_inter4<<<256, 1024, 0, stream>>>(xwi, Ui, Wp, bp, rnnI, gates, hstate, ustate,
                                           (int)t0, nt);
    k_fcln<1><<<(unsigned)(32 * nt), 256, 0, stream>>>(rnnI, Wfc2, bfc2, gam2, bet2, io, outp,
                                                       t0 * 1024);
  }
}

// Round 5
// 1792.479 us; speedup vs baseline: 1.1783x; 1.0503x over previous
//
#include <hip/hip_runtime.h>
#include <cmath>

// ============================================================================
// DPRNN block (intra BiGRU + inter Skip-GRU), all fp32.
// NUMERICS: inter skip-GRU binary gate round(sigmoid(h@Wp)) -> keep fp32.
// Round 5: BALANCED wave roles. Rounds 3/4 wave-specialized (zr waves idle in
// phase B and vice versa -> ~50% idle, VALUBusy 53%). Now every wave holds
// both a zr k-slice and an hh k-slice of U (48 regs) and works in BOTH
// phases. Per-seq and per-block u==0 skip retained (bit-exact).
// ============================================================================

typedef float f32x16 __attribute__((ext_vector_type(16)));

__device__ __forceinline__ float sigf(float x) { return 1.0f / (1.0f + expf(-x)); }
__device__ __forceinline__ float rlanef(float v, int l) {
  return __uint_as_float(__builtin_amdgcn_readlane(__float_as_uint(v), (unsigned)l));
}

// 16-k MAC, 2 column groups
template <int SB>
__device__ __forceinline__ void macP2(const f32x16& u0, const f32x16& u1, float hv,
                                      float& a0, float& a1) {
#pragma unroll
  for (int k = 0; k < 16; ++k) {
    const float hs = rlanef(hv, SB + k);
    a0 = fmaf(u0[k], hs, a0);
    a1 = fmaf(u1[k], hs, a1);
  }
}
// 16-k MAC, 1 column group
template <int SB>
__device__ __forceinline__ void macP1(const f32x16& u, float hv, float& a) {
#pragma unroll
  for (int k = 0; k < 16; ++k) a = fmaf(u[k], rlanef(hv, SB + k), a);
}

// ---------------------------------------------------------------- fill ones
__global__ __launch_bounds__(256) void k_fill_ones(float* __restrict__ p, int n) {
  int i = blockIdx.x * 256 + threadIdx.x;
  if (i < n) p[i] = 1.0f;
}

// ---------------------------------------------------------------- GEMM (xw precompute)
enum { MA_X_FWD = 0, MA_X_BWD = 1, MA_INTER = 2 };

template <int MODE>
__global__ __launch_bounds__(256) void k_gemm_xw(
    const float* __restrict__ A0, const float* __restrict__ A1,
    const float* __restrict__ Bm, const float* __restrict__ bias,
    float* __restrict__ Cm, long M0, int N, int K, int KT)
{
  __shared__ float As[16][68];
  __shared__ float Bs[16][68];
  const int tid = threadIdx.x;
  const int tx = tid & 15, ty = tid >> 4;
  const long row0g = M0 + (long)blockIdx.x * 64;
  const int col0 = blockIdx.y * 64;
  const int lr = tid >> 2;
  const int lk4 = (tid & 3) * 4;
  const int bk = tid >> 4;
  const int bc4 = (tid & 15) * 4;
  float acc[4][4];
#pragma unroll
  for (int i = 0; i < 4; ++i)
#pragma unroll
    for (int j = 0; j < 4; ++j) acc[i][j] = 0.f;

  for (int kt = 0; kt < KT; ++kt) {
    const int k0 = kt * 16;
    {
      const long rg = row0g + lr;
      float v0, v1, v2, v3;
      if (MODE == MA_X_FWD) {
        const float4 a4 = *reinterpret_cast<const float4*>(&A0[rg * 128 + k0 + lk4]);
        v0 = a4.x; v1 = a4.y; v2 = a4.z; v3 = a4.w;
      } else if (MODE == MA_X_BWD) {
        const long s = rg >> 6; const int t = (int)(rg & 63);
        const float4 a4 =
            *reinterpret_cast<const float4*>(&A0[(s * 64 + (63 - t)) * 128 + k0 + lk4]);
        v0 = a4.x; v1 = a4.y; v2 = a4.z; v3 = a4.w;
      } else {  // MA_INTER: rg = l*1024 + n
        const int n = (int)(rg & 1023);
        const int l = (int)(rg >> 10);
        const long rowc = ((long)(n >> 6) * 200 + l) * 64 + (n & 63);
        const long base = rowc * 128;
        if (kt < 8) {
          const float4 a4 = *reinterpret_cast<const float4*>(&A0[base + k0 + lk4]);
          v0 = a4.x; v1 = a4.y; v2 = a4.z; v3 = a4.w;
        } else {
          v0 = (lk4 == 0) ? A1[rowc] : 0.f;
          v1 = 0.f; v2 = 0.f; v3 = 0.f;
        }
      }
      As[lk4 + 0][lr] = v0;
      As[lk4 + 1][lr] = v1;
      As[lk4 + 2][lr] = v2;
      As[lk4 + 3][lr] = v3;
    }
    {
      const int k = k0 + bk;
      float4 b4 = make_float4(0.f, 0.f, 0.f, 0.f);
      if (k < K) b4 = *reinterpret_cast<const float4*>(&Bm[(long)k * N + col0 + bc4]);
      *reinterpret_cast<float4*>(&Bs[bk][bc4]) = b4;
    }
    __syncthreads();
#pragma unroll
    for (int kk = 0; kk < 16; ++kk) {
      const float4 a4 = *reinterpret_cast<const float4*>(&As[kk][ty * 4]);
      const float4 b4 = *reinterpret_cast<const float4*>(&Bs[kk][tx * 4]);
      const float av[4] = {a4.x, a4.y, a4.z, a4.w};
      const float bv[4] = {b4.x, b4.y, b4.z, b4.w};
#pragma unroll
      for (int i = 0; i < 4; ++i)
#pragma unroll
        for (int j = 0; j < 4; ++j) acc[i][j] = fmaf(av[i], bv[j], acc[i][j]);
    }
    __syncthreads();
  }
  const float4 bi4 = *reinterpret_cast<const float4*>(&bias[col0 + tx * 4]);
  const float bv[4] = {bi4.x, bi4.y, bi4.z, bi4.w};
#pragma unroll
  for (int i = 0; i < 4; ++i) {
    const long rl = (long)blockIdx.x * 64 + ty * 4 + i;
    float4 o;
    o.x = acc[i][0] + bv[0];
    o.y = acc[i][1] + bv[1];
    o.z = acc[i][2] + bv[2];
    o.w = acc[i][3] + bv[3];
    *reinterpret_cast<float4*>(&Cm[rl * (long)N + col0 + tx * 4]) = o;
  }
}

// ---------------------------------------------------------------- intra GRU v4 (balanced)
// 256 thr (4 waves), 4 seqs, one dir per blockIdx.y. Every wave: k-slice w*16
// of ALL of {z,r,hh}. Phase A: cols z=lane, r=64+lane. Phase B: col=lane.
// Combine/summer: wave w = seq w.
__global__ __launch_bounds__(256, 4) void k_gru_intra4(
    const float* __restrict__ xwf, const float* __restrict__ xwb,
    const float* __restrict__ Uf, const float* __restrict__ Ub,
    float* __restrict__ rnn)
{
  const int dir = blockIdx.y;
  const float* __restrict__ xw = dir ? xwb : xwf;
  const float* __restrict__ U  = dir ? Ub : Uf;
  __shared__ float h8[4][64], z8[4][64], rh8[4][64];
  __shared__ float pA[4][4][128];
  __shared__ float pB[4][4][64];
  const int tid = threadIdx.x;
  const int w = tid >> 6, lane = tid & 63;
  const long s0 = (long)blockIdx.x * 4;

  f32x16 uz, ur, uhh;  // k-slice w*16..+15, all three gate blocks
#pragma unroll
  for (int k = 0; k < 16; ++k) {
    const int row = (w * 16 + k) * 192;
    uz[k]  = U[row + lane];
    ur[k]  = U[row + 64 + lane];
    uhh[k] = U[row + 128 + lane];
  }
  h8[w][lane] = 0.f;
  __syncthreads();

  const long xrow0 = (s0 + w) * 64;  // this wave's combiner/summer sequence
  float xa1 = xw[xrow0 * 192 + lane];
  float xa2 = xw[xrow0 * 192 + 64 + lane];
  float xb  = xw[xrow0 * 192 + 128 + lane];

  for (int t = 0; t < 64; ++t) {
    const int tn = (t < 63) ? t + 1 : t;
    const float xa1n = xw[(xrow0 + tn) * 192 + lane];
    const float xa2n = xw[(xrow0 + tn) * 192 + 64 + lane];
    const float xbn  = xw[(xrow0 + tn) * 192 + 128 + lane];
    {  // ---- phase A: all 4 waves, k-slice w*16..+15 ----
      const float hv01 = h8[lane >> 5][w * 16 + (lane & 15)];      // seqs 0,1
      const float hv23 = h8[2 + (lane >> 5)][w * 16 + (lane & 15)];  // seqs 2,3
      float az0 = 0.f, ar0 = 0.f, az1 = 0.f, ar1 = 0.f;
      float az2 = 0.f, ar2 = 0.f, az3 = 0.f, ar3 = 0.f;
      macP2<0>(uz, ur, hv01, az0, ar0);
      macP2<32>(uz, ur, hv01, az1, ar1);
      macP2<0>(uz, ur, hv23, az2, ar2);
      macP2<32>(uz, ur, hv23, az3, ar3);
      pA[0][w][lane] = az0; pA[0][w][64 + lane] = ar0;
      pA[1][w][lane] = az1; pA[1][w][64 + lane] = ar1;
      pA[2][w][lane] = az2; pA[2][w][64 + lane] = ar2;
      pA[3][w][lane] = az3; pA[3][w][64 + lane] = ar3;
    }
    __syncthreads();  // b1: pA ready
    {  // combine: wave w = seq w
      const float sz = pA[w][0][lane] + pA[w][1][lane] + pA[w][2][lane] +
                       pA[w][3][lane] + xa1;
      const float sr = pA[w][0][64 + lane] + pA[w][1][64 + lane] +
                       pA[w][2][64 + lane] + pA[w][3][64 + lane] + xa2;
      z8[w][lane] = sigf(sz);
      rh8[w][lane] = sigf(sr) * h8[w][lane];
    }
    __syncthreads();  // b2: z8, rh8 ready
    {  // ---- phase B: all 4 waves, k-slice w*16..+15, col = lane ----
      const float rv01 = rh8[lane >> 5][w * 16 + (lane & 15)];
      const float rv23 = rh8[2 + (lane >> 5)][w * 16 + (lane & 15)];
      float a0 = 0.f, a1 = 0.f, a2 = 0.f, a3 = 0.f;
      macP1<0>(uhh, rv01, a0);
      macP1<32>(uhh, rv01, a1);
      macP1<0>(uhh, rv23, a2);
      macP1<32>(uhh, rv23, a3);
      pB[0][w][lane] = a0;
      pB[1][w][lane] = a1;
      pB[2][w][lane] = a2;
      pB[3][w][lane] = a3;
    }
    __syncthreads();  // b3: pB ready
    {  // summer: wave w = seq w, col = lane
      const float pre = pB[w][0][lane] + pB[w][1][lane] + pB[w][2][lane] +
                        pB[w][3][lane] + xb;
      const float hh = tanhf(pre);
      const float z = z8[w][lane];
      const float ho = h8[w][lane];
      const float hn = z * ho + (1.f - z) * hh;
      h8[w][lane] = hn;
      const int tt = dir ? (63 - t) : t;
      rnn[((s0 + w) * 64 + tt) * 128 + dir * 64 + lane] = hn;
    }
    __syncthreads();  // b4: h8 ready for next step
    xa1 = xa1n; xa2 = xa2n; xb = xbn;
  }
}

// ---------------------------------------------------------------- inter skip-GRU v5 (balanced)
// 256 blocks x 1024 thr (16 waves), 4 seqs/block, t-chunked [t0, t0+nt).
// Every wave: kslice kA=(w&7)*16 and col-half cH=(w>>3).
// Phase A: cols {cH*128+lane, cH*128+64+lane} of zr (256) -> 32 U regs.
// Phase B: col {cH*64+lane} of hh (128)                   -> 16 U regs.
// CombineA: thread (s=tid>>8, c=tid&255). Summer+gate: waves 0..3 (seq=w).
// u==0 skip: block-level (all phases) + per-seq guards.
__global__ __launch_bounds__(1024, 4) void k_gru_inter5(
    const float* __restrict__ xw, const float* __restrict__ Ui,
    const float* __restrict__ Wp, const float* __restrict__ bp,
    float* __restrict__ rnn, float* __restrict__ gates,
    float* __restrict__ hstate, float* __restrict__ ustate,
    int t0, int nt)
{
  __shared__ float h4[4][128], z4[4][128], rh4[4][128];
  __shared__ float pA[4][8][256];
  __shared__ float pB[4][8][128];
  __shared__ float uu[4], utt[4];
  const int tid = threadIdx.x;
  const int w = tid >> 6, lane = tid & 63;
  const int n0 = blockIdx.x * 4;
  const int kA = (w & 7) * 16;   // k-slice base (shared by A and B roles)
  const int cH = w >> 3;         // column half

  f32x16 uzA, uzB, uh;
#pragma unroll
  for (int k = 0; k < 16; ++k) {
    const long r = (long)(kA + k) * 384;
    uzA[k] = Ui[r + cH * 128 + lane];
    uzB[k] = Ui[r + cH * 128 + 64 + lane];
    uh[k]  = Ui[r + 256 + cH * 64 + lane];
  }
  if (tid < 512) {
    const int s = tid >> 7, c = tid & 127;
    h4[s][c] = (t0 == 0) ? 0.f : hstate[(long)(n0 + s) * 128 + c];
  }
  if (tid < 4) {
    utt[tid] = (t0 == 0) ? 1.f : ustate[n0 + tid];
    uu[tid]  = (t0 == 0) ? 1.f : ustate[1024 + n0 + tid];
  }
  const float bp0 = bp[0];
  float wprA = 0.f, wprB = 0.f;
  if (w < 4) { wprA = Wp[lane]; wprB = Wp[64 + lane]; }
  __syncthreads();

  // prefetch xw for dl=0
  const int sC = tid >> 8;        // combineA seq
  const int cC = tid & 255;       // combineA zr col
  float xc = xw[(long)(n0 + sC) * 384 + cC];
  float xbA = 0.f, xbB = 0.f;
  if (w < 4) {
    xbA = xw[(long)(n0 + w) * 384 + 256 + lane];
    xbB = xw[(long)(n0 + w) * 384 + 320 + lane];
  }

  for (int dl = 0; dl < nt; ++dl) {
    const float u0g = uu[0], u1g = uu[1], u2g = uu[2], u3g = uu[3];
    const bool act = (u0g + u1g + u2g + u3g) != 0.f;
    const int dn = (dl + 1 < nt) ? dl + 1 : dl;
    const float xcn = xw[((long)dn * 1024 + n0 + sC) * 384 + cC];
    float xbAn = 0.f, xbBn = 0.f;
    if (w < 4) {
      xbAn = xw[((long)dn * 1024 + n0 + w) * 384 + 256 + lane];
      xbBn = xw[((long)dn * 1024 + n0 + w) * 384 + 320 + lane];
    }
    if (act) {
      {  // ---- phase A: all 16 waves ----
        const float hv01 = h4[lane >> 5][kA + (lane & 15)];      // seqs 0,1
        const float hv23 = h4[2 + (lane >> 5)][kA + (lane & 15)];  // seqs 2,3
        const int kq = w & 7;
        if (u0g != 0.f) {
          float a0 = 0.f, a1 = 0.f;
          macP2<0>(uzA, uzB, hv01, a0, a1);
          pA[0][kq][cH * 128 + lane] = a0;
          pA[0][kq][cH * 128 + 64 + lane] = a1;
        }
        if (u1g != 0.f) {
          float a0 = 0.f, a1 = 0.f;
          macP2<32>(uzA, uzB, hv01, a0, a1);
          pA[1][kq][cH * 128 + lane] = a0;
          pA[1][kq][cH * 128 + 64 + lane] = a1;
        }
        if (u2g != 0.f) {
          float a0 = 0.f, a1 = 0.f;
          macP2<0>(uzA, uzB, hv23, a0, a1);
          pA[2][kq][cH * 128 + lane] = a0;
          pA[2][kq][cH * 128 + 64 + lane] = a1;
        }
        if (u3g != 0.f) {
          float a0 = 0.f, a1 = 0.f;
          macP2<32>(uzA, uzB, hv23, a0, a1);
          pA[3][kq][cH * 128 + lane] = a0;
          pA[3][kq][cH * 128 + 64 + lane] = a1;
        }
      }
      __syncthreads();  // b1
      {  // combineA: thread (sC, cC)
        if (uu[sC] != 0.f) {
          float sum = xc;
#pragma unroll
          for (int q = 0; q < 8; ++q) sum += pA[sC][q][cC];
          if (cC < 128) z4[sC][cC] = sigf(sum);
          else rh4[sC][cC - 128] = sigf(sum) * h4[sC][cC - 128];
        }
      }
      __syncthreads();  // b2
      {  // ---- phase B: all 16 waves, col cH*64+lane ----
        const float rv01 = rh4[lane >> 5][kA + (lane & 15)];
        const float rv23 = rh4[2 + (lane >> 5)][kA + (lane & 15)];
        const int kq = w & 7;
        if (u0g != 0.f) {
          float b = 0.f; macP1<0>(uh, rv01, b);
          pB[0][kq][cH * 64 + lane] = b;
        }
        if (u1g != 0.f) {
          float b = 0.f; macP1<32>(uh, rv01, b);
          pB[1][kq][cH * 64 + lane] = b;
        }
        if (u2g != 0.f) {
          float b = 0.f; macP1<0>(uh, rv23, b);
          pB[2][kq][cH * 64 + lane] = b;
        }
        if (u3g != 0.f) {
          float b = 0.f; macP1<32>(uh, rv23, b);
          pB[3][kq][cH * 64 + lane] = b;
        }
      }
      __syncthreads();  // b3
    }
    if (w < 4) {  // summer + gate, seq = w
      const float us = uu[w];
      const float hoA = h4[w][lane], hoB = h4[w][64 + lane];
      float hqA, hqB;
      if (us != 0.f) {
        float sA = xbA, sB = xbB;
#pragma unroll
        for (int q = 0; q < 8; ++q) {
          sA += pB[w][q][lane];
          sB += pB[w][q][64 + lane];
        }
        const float hhA = tanhf(sA), hhB = tanhf(sB);
        const float zA = z4[w][lane], zB = z4[w][64 + lane];
        hqA = zA * hoA + (1.f - zA) * hhA;
        hqB = zB * hoB + (1.f - zB) * hhB;
        h4[w][lane] = hqA;
        h4[w][64 + lane] = hqB;
      } else {
        hqA = hoA; hqB = hoB;
      }
      rnn[((long)dl * 1024 + n0 + w) * 128 + lane] = hqA;
      rnn[((long)dl * 1024 + n0 + w) * 128 + 64 + lane] = hqB;
      // gate: 64-lane butterfly
      float p = hqA * wprA + hqB * wprB;
      p += __shfl_xor(p, 32);
      p += __shfl_xor(p, 16);
      p += __shfl_xor(p, 8);
      p += __shfl_xor(p, 4);
      p += __shfl_xor(p, 2);
      p += __shfl_xor(p, 1);
      const float delta = sigf(p + bp0);
      const float ut = utt[w];
      const float utn = us * delta + (1.f - us) * (ut + fminf(delta, 1.f - ut));
      if (lane == 0) {
        gates[(long)(n0 + w) * 200 + t0 + dl] = us;
        utt[w] = utn;
        uu[w] = rintf(utn);  // half-to-even, matches jnp.round
      }
    }
    __syncthreads();  // b4: h4/uu ready for next step
    xc = xcn; xbA = xbAn; xbB = xbBn;
  }
  if (tid < 512) {
    const int s = tid >> 7, c = tid & 127;
    hstate[(long)(n0 + s) * 128 + c] = h4[s][c];
  }
  if (tid < 4) {
    ustate[n0 + tid] = utt[tid];
    ustate[1024 + n0 + tid] = uu[tid];
  }
}

// ---------------------------------------------------------------- FC + LayerNorm + residual
template <int OM>  // 0 = intra (direct rows), 1 = inter (rows rg = l*1024 + n)
__global__ __launch_bounds__(256) void k_fcln(
    const float* __restrict__ A, const float* __restrict__ Wt,
    const float* __restrict__ bias, const float* __restrict__ gamma,
    const float* __restrict__ beta, const float* __restrict__ resid,
    float* __restrict__ dst, long M0)
{
  __shared__ float As[16][36];
  __shared__ float Bs[16][132];
  __shared__ float red0[32][33];
  __shared__ float red1[32][33];
  __shared__ float mu_s[32];
  __shared__ float rs_s[32];
  const int tid = threadIdx.x;
  const int tx = tid & 31, ty = tid >> 5;
  const long r0l = (long)blockIdx.x * 32;
  const int lr = tid >> 3;
  const int lk2 = (tid & 7) * 2;
  const int bkk = tid >> 4;
  const int bc8 = (tid & 15) * 8;
  float acc[4][4];
#pragma unroll
  for (int i = 0; i < 4; ++i)
#pragma unroll
    for (int j = 0; j < 4; ++j) acc[i][j] = 0.f;

  for (int kt = 0; kt < 8; ++kt) {
    const int k0 = kt * 16;
    const float2 a2 = *reinterpret_cast<const float2*>(&A[(r0l + lr) * 128 + k0 + lk2]);
    As[lk2][lr] = a2.x;
    As[lk2 + 1][lr] = a2.y;
    const float4 w0 = *reinterpret_cast<const float4*>(&Wt[(long)(k0 + bkk) * 128 + bc8]);
    const float4 w1 = *reinterpret_cast<const float4*>(&Wt[(long)(k0 + bkk) * 128 + bc8 + 4]);
    *reinterpret_cast<float4*>(&Bs[bkk][bc8]) = w0;
    *reinterpret_cast<float4*>(&Bs[bkk][bc8 + 4]) = w1;
    __syncthreads();
#pragma unroll
    for (int kk = 0; kk < 16; ++kk) {
      const float4 a4 = *reinterpret_cast<const float4*>(&As[kk][ty * 4]);
      const float4 b4 = *reinterpret_cast<const float4*>(&Bs[kk][tx * 4]);
      const float av[4] = {a4.x, a4.y, a4.z, a4.w};
      const float bv[4] = {b4.x, b4.y, b4.z, b4.w};
#pragma unroll
      for (int i = 0; i < 4; ++i)
#pragma unroll
        for (int j = 0; j < 4; ++j) acc[i][j] = fmaf(av[i], bv[j], acc[i][j]);
    }
    __syncthreads();
  }
  {
    const float4 bb4 = *reinterpret_cast<const float4*>(&bias[tx * 4]);
    const float bv[4] = {bb4.x, bb4.y, bb4.z, bb4.w};
#pragma unroll
    for (int i = 0; i < 4; ++i)
#pragma unroll
      for (int j = 0; j < 4; ++j) acc[i][j] += bv[j];
  }
#pragma unroll
  for (int i = 0; i < 4; ++i) {
    const float s = acc[i][0] + acc[i][1] + acc[i][2] + acc[i][3];
    const float q = acc[i][0] * acc[i][0] + acc[i][1] * acc[i][1] +
                    acc[i][2] * acc[i][2] + acc[i][3] * acc[i][3];
    red0[ty * 4 + i][tx] = s;
    red1[ty * 4 + i][tx] = q;
  }
  __syncthreads();
  if (tid < 32) {
    float s = 0.f, q = 0.f;
#pragma unroll
    for (int j = 0; j < 32; ++j) { s += red0[tid][j]; q += red1[tid][j]; }
    const float mu = s * (1.0f / 128.0f);
    const float var = q * (1.0f / 128.0f) - mu * mu;
    mu_s[tid] = mu;
    rs_s[tid] = 1.0f / sqrtf(var + 1e-8f);
  }
  __syncthreads();
  const float4 g4 = *reinterpret_cast<const float4*>(&gamma[tx * 4]);
  const float4 be4 = *reinterpret_cast<const float4*>(&beta[tx * 4]);
#pragma unroll
  for (int i = 0; i < 4; ++i) {
    const int rloc = ty * 4 + i;
    const long rg = M0 + r0l + rloc;
    long off;
    if (OM == 0) {
      off = rg * 128 + tx * 4;
    } else {
      const int n = (int)(rg & 1023);
      const int l = (int)(rg >> 10);
      off = (((long)(n >> 6) * 200 + l) * 64 + (n & 63)) * 128 + tx * 4;
    }
    const float4 r4 = *reinterpret_cast<const float4*>(&resid[off]);
    const float mu = mu_s[rloc], rs = rs_s[rloc];
    float4 o;
    o.x = (acc[i][0] - mu) * rs * g4.x + be4.x + r4.x;
    o.y = (acc[i][1] - mu) * rs * g4.y + be4.y + r4.y;
    o.z = (acc[i][2] - mu) * rs * g4.z + be4.z + r4.z;
    o.w = (acc[i][3] - mu) * rs * g4.w + be4.w + r4.w;
    *reinterpret_cast<float4*>(&dst[off]) = o;
  }
}

// ============================================================================
extern "C" void kernel_launch(void* const* d_in, const int* in_sizes, int n_in,
                              void* d_out, int out_size, void* d_ws, size_t ws_size,
                              hipStream_t stream)
{
  (void)in_sizes; (void)n_in; (void)out_size;
  const float* x    = (const float*)d_in[0];
  const float* scl  = (const float*)d_in[1];
  const float* Wf   = (const float*)d_in[2];
  const float* Uf   = (const float*)d_in[3];
  const float* bf   = (const float*)d_in[4];
  const float* Wb   = (const float*)d_in[5];
  const float* Ub   = (const float*)d_in[6];
  const float* bb   = (const float*)d_in[7];
  const float* Wfc1 = (const float*)d_in[8];
  const float* bfc1 = (const float*)d_in[9];
  const float* gam1 = (const float*)d_in[10];
  const float* bet1 = (const float*)d_in[11];
  const float* Wi   = (const float*)d_in[12];
  const float* Ui   = (const float*)d_in[13];
  const float* bi   = (const float*)d_in[14];
  const float* Wp   = (const float*)d_in[15];
  const float* bp   = (const float*)d_in[16];
  const float* Wfc2 = (const float*)d_in[17];
  const float* bfc2 = (const float*)d_in[18];
  const float* gam2 = (const float*)d_in[19];
  const float* bet2 = (const float*)d_in[20];

  float* outp  = (float*)d_out;
  float* io    = outp;                         // intra_out lives here
  float* onesp = outp + 26214400L;
  float* gates = outp + 26214400L + 12800L;
  float* ws    = (float*)d_ws;
  const long wsf = (long)(ws_size / sizeof(float));

  k_fill_ones<<<50, 256, 0, stream>>>(onesp, 12800);

  // ---------------- intra pass (seq-chunked) ----------------
  long cnI = (wsf / 32768L) & ~7L;
  if (cnI > 3200) cnI = 3200;
  if (cnI < 8) cnI = 8;
  for (long s0 = 0; s0 < 3200; s0 += cnI) {
    const long cn = (3200 - s0 < cnI) ? (3200 - s0) : cnI;
    float* xwf = ws;
    float* xwb = ws + cn * 12288L;
    float* rnn = ws + cn * 24576L;
    const long M = cn * 64;
    dim3 gg((unsigned)(M / 64), 3);
    k_gemm_xw<MA_X_FWD><<<gg, 256, 0, stream>>>(x, nullptr, Wf, bf, xwf, s0 * 64, 192, 128, 8);
    k_gemm_xw<MA_X_BWD><<<gg, 256, 0, stream>>>(x, nullptr, Wb, bb, xwb, s0 * 64, 192, 128, 8);
    dim3 gr((unsigned)(cn / 4), 2);
    k_gru_intra4<<<gr, 256, 0, stream>>>(xwf, xwb, Uf, Ub, rnn);
    k_fcln<0><<<(unsigned)(M / 32), 256, 0, stream>>>(rnn, Wfc1, bfc1, gam1, bet1, x, io, s0 * 64);
  }

  // ---------------- inter pass (t-chunked) ----------------
  const long per_t = 1024L * 384 + 1024L * 128;  // floats per time step
  const long state_f = 1024L * 128 + 3072L;
  long nt_alloc = (wsf - state_f) / per_t;
  if (nt_alloc > 200) nt_alloc = 200;
  if (nt_alloc < 1) nt_alloc = 1;
  float* xwi    = ws;
  float* rnnI   = ws + nt_alloc * 1024L * 384;
  float* hstate = rnnI + nt_alloc * 1024L * 128;
  float* ustate = hstate + 1024L * 128;

  for (long t0 = 0; t0 < 200; t0 += nt_alloc) {
    const int nt = (int)((200 - t0 < nt_alloc) ? (200 - t0) : nt_alloc);
    dim3 gg((unsigned)(16 * nt), 6);
    k_gemm_xw<MA_INTER><<<gg, 256, 0, stream>>>(io, scl, Wi, bi, xwi, t0 * 1024, 384, 129, 9);
    k_gru_inter5<<<256, 1024, 0, stream>>>(xwi, Ui, Wp, bp, rnnI, gates, hstate, ustate,
                                           (int)t0, nt);
    k_fcln<1><<<(unsigned)(32 * nt), 256, 0, stream>>>(rnnI, Wfc2, bfc2, gam2, bet2, io, outp,
                                                       t0 * 1024);
  }
}